// Round 1
// baseline (1367.669 us; speedup 1.0000x reference)
//
#include <hip/hip_runtime.h>
#include <math.h>

// Problem constants
#define Bb   1024
#define NI   50000
#define NU   20000
#define Dd   256
#define Hh   4
#define MAXNB 20
#define Tt   1000

typedef __bf16 bf16x8 __attribute__((ext_vector_type(8)));
typedef float  f32x4  __attribute__((ext_vector_type(4)));

__device__ __forceinline__ unsigned short f2bf(float f) {
  unsigned u = __float_as_uint(f);
  u += 0x7FFFu + ((u >> 16) & 1u);   // RNE
  return (unsigned short)(u >> 16);
}

__device__ __forceinline__ void cvt_store4(unsigned short* d, float4 v) {
  ushort4 u;
  u.x = f2bf(v.x); u.y = f2bf(v.y); u.z = f2bf(v.z); u.w = f2bf(v.w);
  *(ushort4*)d = u;
}

__device__ __forceinline__ f32x4 mfma16(const unsigned short* a, const unsigned short* b, f32x4 c) {
  typedef unsigned short u16x8 __attribute__((ext_vector_type(8)));
  u16x8 av = *(const u16x8*)a;
  u16x8 bv = *(const u16x8*)b;
  return __builtin_amdgcn_mfma_f32_16x16x32_bf16(
      __builtin_bit_cast(bf16x8, av), __builtin_bit_cast(bf16x8, bv), c, 0, 0, 0);
}

__device__ __forceinline__ float gelu_f(float x) {
  return 0.5f * x * (1.f + erff(x * 0.70710678118654752f));
}

// ---------------------------------------------------------------------------
// Small NT GEMM: C[M,N] = epi(A[M,K] @ B[N,K]^T). M,N mult of 64, K mult of 32.
// EPI: 1 = +bias ; 2 = gelu(+bias) ; 3 = +bias + E[m,n]
// ---------------------------------------------------------------------------
template<int EPI>
__global__ __launch_bounds__(256) void gemm_nt(
    const float* __restrict__ A, const float* __restrict__ Bm,
    const float* __restrict__ bias, const float* __restrict__ E,
    float* __restrict__ C, int M, int N, int K)
{
  __shared__ __align__(16) unsigned short As[64 * 40];  // pad 32->40 breaks bank stride
  __shared__ __align__(16) unsigned short Bs[64 * 40];
  const int tid = threadIdx.x;
  const int m0 = blockIdx.x * 64, n0 = blockIdx.y * 64;
  const int w = tid >> 6, l = tid & 63;
  const int wm = (w >> 1) * 32, wn = (w & 1) * 32;
  const int sr = tid >> 3, sc = (tid & 7) * 4;
  const int fr = l & 15, fo = (l >> 4) * 8;
  f32x4 acc[2][2] = {};
  for (int k0 = 0; k0 < K; k0 += 32) {
#pragma unroll
    for (int half = 0; half < 2; ++half) {
      int row = sr + half * 32;
      cvt_store4(&As[row * 40 + sc], *(const float4*)(A  + (size_t)(m0 + row) * K + k0 + sc));
      cvt_store4(&Bs[row * 40 + sc], *(const float4*)(Bm + (size_t)(n0 + row) * K + k0 + sc));
    }
    __syncthreads();
    const unsigned short* ap0 = &As[(wm +      fr) * 40 + fo];
    const unsigned short* ap1 = &As[(wm + 16 + fr) * 40 + fo];
    const unsigned short* bp0 = &Bs[(wn +      fr) * 40 + fo];
    const unsigned short* bp1 = &Bs[(wn + 16 + fr) * 40 + fo];
    acc[0][0] = mfma16(ap0, bp0, acc[0][0]);
    acc[0][1] = mfma16(ap0, bp1, acc[0][1]);
    acc[1][0] = mfma16(ap1, bp0, acc[1][0]);
    acc[1][1] = mfma16(ap1, bp1, acc[1][1]);
    __syncthreads();
  }
  const int cr = (l >> 4) * 4, cc = l & 15;
#pragma unroll
  for (int i = 0; i < 2; ++i)
#pragma unroll
    for (int j = 0; j < 2; ++j) {
      int n = n0 + wn + 16 * j + cc;
      float bv = bias[n];
#pragma unroll
      for (int r = 0; r < 4; ++r) {
        int m = m0 + wm + 16 * i + cr + r;
        float v = acc[i][j][r] + bv;
        if (EPI == 2) v = gelu_f(v);
        if (EPI == 3) v += E[(size_t)m * N + n];
        C[(size_t)m * N + n] = v;
      }
    }
}

// ---------------------------------------------------------------------------
// GEMM1: Cacc(1024x512) += x0(1024x50000) @ enc_w1(512x50000)^T, split-K atomic
// ---------------------------------------------------------------------------
__global__ __launch_bounds__(256) void gemm1_enc(
    const float* __restrict__ A, const float* __restrict__ Bm,
    float* __restrict__ Cacc, int K, int kchunk)
{
  __shared__ __align__(16) unsigned short As[128 * 40];
  __shared__ __align__(16) unsigned short Bs[128 * 40];
  const int tid = threadIdx.x;
  const int m0 = blockIdx.x * 128, n0 = blockIdx.y * 128;
  const int kb = blockIdx.z * kchunk;
  const int ke = (K < kb + kchunk) ? K : (kb + kchunk);
  const int w = tid >> 6, l = tid & 63;
  const int wm = (w >> 1) * 64, wn = (w & 1) * 64;
  const int sr = tid >> 3, sc = (tid & 7) * 4;
  const int fr = l & 15, fo = (l >> 4) * 8;
  f32x4 acc[4][4] = {};
  for (int k0 = kb; k0 < ke; k0 += 32) {
#pragma unroll
    for (int half = 0; half < 4; ++half) {
      int row = sr + half * 32;
      int kg = k0 + sc;
      float4 av = (kg < ke) ? *(const float4*)(A  + (size_t)(m0 + row) * K + kg)
                            : make_float4(0.f, 0.f, 0.f, 0.f);
      float4 bv = (kg < ke) ? *(const float4*)(Bm + (size_t)(n0 + row) * K + kg)
                            : make_float4(0.f, 0.f, 0.f, 0.f);
      cvt_store4(&As[row * 40 + sc], av);
      cvt_store4(&Bs[row * 40 + sc], bv);
    }
    __syncthreads();
    const unsigned short *ap[4], *bp[4];
#pragma unroll
    for (int i = 0; i < 4; ++i) {
      ap[i] = &As[(wm + 16 * i + fr) * 40 + fo];
      bp[i] = &Bs[(wn + 16 * i + fr) * 40 + fo];
    }
#pragma unroll
    for (int i = 0; i < 4; ++i)
#pragma unroll
      for (int j = 0; j < 4; ++j)
        acc[i][j] = mfma16(ap[i], bp[j], acc[i][j]);
    __syncthreads();
  }
  const int cr = (l >> 4) * 4, cc = l & 15;
#pragma unroll
  for (int i = 0; i < 4; ++i)
#pragma unroll
    for (int j = 0; j < 4; ++j) {
      int n = n0 + wn + 16 * j + cc;
#pragma unroll
      for (int r = 0; r < 4; ++r) {
        int m = m0 + wm + 16 * i + cr + r;
        atomicAdd(&Cacc[(size_t)m * 512 + n], acc[i][j][r]);
      }
    }
}

// H1 = gelu(H1acc + enc_b1), in place. 1024x512.
__global__ __launch_bounds__(256) void h1_epi(float* __restrict__ H, const float* __restrict__ b) {
  int i = blockIdx.x * 256 + threadIdx.x;
  H[i] = gelu_f(H[i] + b[i & 511]);
}

// ---------------------------------------------------------------------------
// Decoder GEMM2 + fused recon loss: acc over softplus(l) - l*x0
// A = G(1024x512), Bm = dec_w2(50000x512), N ragged (50000)
// ---------------------------------------------------------------------------
__global__ __launch_bounds__(256) void dec_loss(
    const float* __restrict__ A, const float* __restrict__ Bm,
    const float* __restrict__ bias, const float* __restrict__ x0,
    float* __restrict__ recon_acc)
{
  const int K = 512, N = NI;
  __shared__ __align__(16) unsigned short As[128 * 40];
  __shared__ __align__(16) unsigned short Bs[128 * 40];
  __shared__ float red[4];
  const int tid = threadIdx.x;
  const int m0 = blockIdx.x * 128, n0 = blockIdx.y * 128;
  const int w = tid >> 6, l = tid & 63;
  const int wm = (w >> 1) * 64, wn = (w & 1) * 64;
  const int sr = tid >> 3, sc = (tid & 7) * 4;
  const int fr = l & 15, fo = (l >> 4) * 8;
  f32x4 acc[4][4] = {};
  for (int k0 = 0; k0 < K; k0 += 32) {
#pragma unroll
    for (int half = 0; half < 4; ++half) {
      int row = sr + half * 32;
      cvt_store4(&As[row * 40 + sc], *(const float4*)(A + (size_t)(m0 + row) * K + k0 + sc));
      int n = n0 + row;
      float4 bv = (n < N) ? *(const float4*)(Bm + (size_t)n * K + k0 + sc)
                          : make_float4(0.f, 0.f, 0.f, 0.f);
      cvt_store4(&Bs[row * 40 + sc], bv);
    }
    __syncthreads();
    const unsigned short *ap[4], *bp[4];
#pragma unroll
    for (int i = 0; i < 4; ++i) {
      ap[i] = &As[(wm + 16 * i + fr) * 40 + fo];
      bp[i] = &Bs[(wn + 16 * i + fr) * 40 + fo];
    }
#pragma unroll
    for (int i = 0; i < 4; ++i)
#pragma unroll
      for (int j = 0; j < 4; ++j)
        acc[i][j] = mfma16(ap[i], bp[j], acc[i][j]);
    __syncthreads();
  }
  const int cr = (l >> 4) * 4, cc = l & 15;
  float ts = 0.f;
#pragma unroll
  for (int j = 0; j < 4; ++j) {
    int n = n0 + wn + 16 * j + cc;
    if (n < N) {
      float bb = bias[n];
#pragma unroll
      for (int i = 0; i < 4; ++i)
#pragma unroll
        for (int r = 0; r < 4; ++r) {
          int m = m0 + wm + 16 * i + cr + r;
          float lg = acc[i][j][r] + bb;
          float sp = fmaxf(lg, 0.f) + __logf(1.f + __expf(-fabsf(lg)));
          ts += sp - lg * x0[(size_t)m * N + n];
        }
    }
  }
  for (int off = 32; off > 0; off >>= 1) ts += __shfl_xor(ts, off);
  if (l == 0) red[w] = ts;
  __syncthreads();
  if (tid == 0) atomicAdd(recon_acc, red[0] + red[1] + red[2] + red[3]);
}

// ---------------------------------------------------------------------------
// prep: z_t = sqrt_ab[t]*z0 + sqrt_1ab[t]*noise ; te = silu(tn*w1+b1)@w2^T + b2
// ---------------------------------------------------------------------------
__global__ __launch_bounds__(256) void prep_k(
    const int* __restrict__ t, const float* __restrict__ z0, const float* __restrict__ noise,
    const float* __restrict__ te_w1, const float* __restrict__ te_b1,
    const float* __restrict__ te_w2, const float* __restrict__ te_b2,
    float* __restrict__ z_t, float* __restrict__ te)
{
  __shared__ float sj[32];
  __shared__ float sch[2];
  int b = blockIdx.x, d = threadIdx.x;
  int ti = t[b];
  float tn = (float)ti / (float)Tt;
  if (d < 32) {
    float a = tn * te_w1[d] + te_b1[d];
    sj[d] = a / (1.f + __expf(-a));     // silu
  }
  if (d == 0) {
    double tt = (double)(ti + 1) / (double)Tt;
    double c  = cos((tt + 0.008) / 1.008 * M_PI * 0.5);
    double c0 = cos((0.008) / 1.008 * M_PI * 0.5);
    double ab = (c * c) / (c0 * c0);
    sch[0] = (float)sqrt(ab);
    sch[1] = (float)sqrt(1.0 - ab);
  }
  __syncthreads();
  float accv = te_b2[d];
#pragma unroll
  for (int j = 0; j < 32; ++j) accv += sj[j] * te_w2[d * 32 + j];
  size_t i = (size_t)b * Dd + d;
  te[i]  = accv;
  z_t[i] = sch[0] * z0[i] + sch[1] * noise[i];
}

// gather neighbors: nb[b*20+j] = item_emb[neighbor_idx[user_ids[b]*20+j]]
__global__ __launch_bounds__(256) void gather_nb(
    const int* __restrict__ uid, const int* __restrict__ nidx,
    const float* __restrict__ emb, float* __restrict__ nb)
{
  int b = blockIdx.x, j = blockIdx.y, d = threadIdx.x;
  int idx = nidx[uid[b] * MAXNB + j];
  nb[((size_t)b * MAXNB + j) * Dd + d] = emb[(size_t)idx * Dd + d];
}

// cross-attention core: 20 keys, one wave per (b, head)
__global__ __launch_bounds__(256) void attn_k(
    const float* __restrict__ qh, const float* __restrict__ kvh, float* __restrict__ o)
{
  int b = blockIdx.x, tid = threadIdx.x;
  int h = tid >> 6, d = tid & 63;
  float qv = qh[(size_t)b * Dd + h * 64 + d];
  const float* kbase = kvh + (size_t)b * MAXNB * 512 + h * 64 + d;
  const float* vbase = kbase + 256;
  float s[MAXNB];
#pragma unroll
  for (int k = 0; k < MAXNB; ++k) {
    float p = qv * kbase[k * 512];
    for (int off = 32; off > 0; off >>= 1) p += __shfl_xor(p, off);
    s[k] = p * 0.125f;  // 1/sqrt(64)
  }
  float mx = s[0];
#pragma unroll
  for (int k = 1; k < MAXNB; ++k) mx = fmaxf(mx, s[k]);
  float sum = 0.f;
#pragma unroll
  for (int k = 0; k < MAXNB; ++k) { s[k] = __expf(s[k] - mx); sum += s[k]; }
  float inv = 1.f / sum;
  float ov = 0.f;
#pragma unroll
  for (int k = 0; k < MAXNB; ++k) ov += s[k] * vbase[k * 512];
  o[(size_t)b * Dd + h * 64 + d] = ov * inv;
}

// LayerNorm(X + Y) row-wise over 256
__global__ __launch_bounds__(256) void ln_k(
    const float* __restrict__ X, const float* __restrict__ Y,
    const float* __restrict__ g, const float* __restrict__ bb, float* __restrict__ out)
{
  __shared__ float rs[4], rs2[4];
  int b = blockIdx.x, d = threadIdx.x;
  size_t i = (size_t)b * Dd + d;
  float v = X[i] + Y[i];
  float s = v, s2 = v * v;
  for (int off = 32; off > 0; off >>= 1) { s += __shfl_xor(s, off); s2 += __shfl_xor(s2, off); }
  int w = d >> 6, l = d & 63;
  if (l == 0) { rs[w] = s; rs2[w] = s2; }
  __syncthreads();
  s  = rs[0] + rs[1] + rs[2] + rs[3];
  s2 = rs2[0] + rs2[1] + rs2[2] + rs2[3];
  float mean = s * (1.f / 256.f);
  float var  = s2 * (1.f / 256.f) - mean * mean;
  out[i] = (v - mean) * rsqrtf(var + 1e-5f) * g[d] + bb[d];
}

// diff loss: sum((zp - z0)^2) -> atomic
__global__ __launch_bounds__(256) void diff_k(
    const float* __restrict__ zp, const float* __restrict__ z0, float* __restrict__ acc)
{
  __shared__ float red[4];
  size_t i = (size_t)blockIdx.x * 256 + threadIdx.x;
  float d = zp[i] - z0[i];
  float s = d * d;
  for (int off = 32; off > 0; off >>= 1) s += __shfl_xor(s, off);
  int w = threadIdx.x >> 6, l = threadIdx.x & 63;
  if (l == 0) red[w] = s;
  __syncthreads();
  if (threadIdx.x == 0) atomicAdd(acc, red[0] + red[1] + red[2] + red[3]);
}

__global__ void final_k(const float* __restrict__ scal, float* __restrict__ out) {
  out[0] = scal[0] * (1.f / (1024.f * 256.f)) + 0.1f * scal[1] * (1.f / (1024.f * 50000.f));
}

// ---------------------------------------------------------------------------
extern "C" void kernel_launch(void* const* d_in, const int* in_sizes, int n_in,
                              void* d_out, int out_size, void* d_ws, size_t ws_size,
                              hipStream_t stream) {
  const float* x0      = (const float*)d_in[0];
  const int*   uid     = (const int*)  d_in[1];
  const int*   t       = (const int*)  d_in[2];
  const float* noise   = (const float*)d_in[3];
  const int*   nidx    = (const int*)  d_in[4];
  const float* item_emb= (const float*)d_in[5];
  const float* enc_w1  = (const float*)d_in[6];
  const float* enc_b1  = (const float*)d_in[7];
  const float* enc_w2  = (const float*)d_in[8];
  const float* enc_b2  = (const float*)d_in[9];
  const float* dec_w1  = (const float*)d_in[10];
  const float* dec_b1  = (const float*)d_in[11];
  const float* dec_w2  = (const float*)d_in[12];
  const float* dec_b2  = (const float*)d_in[13];
  const float* up_w    = (const float*)d_in[14];
  const float* up_b    = (const float*)d_in[15];
  const float* ip_w    = (const float*)d_in[16];
  const float* ip_b    = (const float*)d_in[17];
  const float* te_w1   = (const float*)d_in[18];
  const float* te_b1   = (const float*)d_in[19];
  const float* te_w2   = (const float*)d_in[20];
  const float* te_b2   = (const float*)d_in[21];
  const float* ca_wqkv = (const float*)d_in[22];
  const float* ca_bqkv = (const float*)d_in[23];
  const float* ca_wo   = (const float*)d_in[24];
  const float* ca_bo   = (const float*)d_in[25];
  const float* sa_wqkv = (const float*)d_in[26];
  const float* sa_bqkv = (const float*)d_in[27];
  const float* sa_wo   = (const float*)d_in[28];
  const float* sa_bo   = (const float*)d_in[29];
  const float* n1_g    = (const float*)d_in[30];
  const float* n1_b    = (const float*)d_in[31];
  const float* n2_g    = (const float*)d_in[32];
  const float* n2_b    = (const float*)d_in[33];
  const float* ff_w1   = (const float*)d_in[34];
  const float* ff_b1   = (const float*)d_in[35];
  const float* ff_w2   = (const float*)d_in[36];
  const float* ff_b2   = (const float*)d_in[37];
  (void)in_sizes; (void)n_in; (void)out_size; (void)ws_size;

  float* ws   = (float*)d_ws;
  float* scal = ws;                    // [0]=diff_sum, [1]=recon_sum
  float* H1   = ws + 4;                // 1024*512 (atomic acc -> gelu in place)
  float* z0   = H1  + 524288;
  float* zt   = z0  + 262144;
  float* te   = zt  + 262144;
  float* qp   = te  + 262144;
  float* qh   = qp  + 262144;
  float* o    = qh  + 262144;
  float* ca   = o   + 262144;
  float* h    = ca  + 262144;
  float* sav  = h   + 262144;
  float* sao  = sav + 262144;
  float* h2   = sao + 262144;
  float* zp   = h2  + 262144;
  float* f1   = zp  + 262144;          // 1024*512
  float* G    = f1  + 524288;          // 1024*512
  float* nb   = G   + 524288;          // 20480*256
  float* kv   = nb  + 5242880;         // 20480*256
  float* kvh  = kv  + 5242880;         // 20480*512

  hipMemsetAsync(d_ws, 0, (size_t)(4 + 524288) * sizeof(float), stream);

  // Encoder big GEMM (split-K=16, chunk 3136)
  gemm1_enc<<<dim3(8, 4, 16), 256, 0, stream>>>(x0, enc_w1, H1, 50000, 3136);
  h1_epi<<<2048, 256, 0, stream>>>(H1, enc_b1);
  gemm_nt<1><<<dim3(16, 4), 256, 0, stream>>>(H1, enc_w2, enc_b2, nullptr, z0, 1024, 256, 512);

  // schedule + time embedding ; q path
  prep_k<<<1024, 256, 0, stream>>>(t, z0, noise, te_w1, te_b1, te_w2, te_b2, zt, te);
  gemm_nt<3><<<dim3(16, 4), 256, 0, stream>>>(zt, up_w, up_b, te, qp, 1024, 256, 256);
  gemm_nt<1><<<dim3(16, 4), 256, 0, stream>>>(qp, ca_wqkv, ca_bqkv, nullptr, qh, 1024, 256, 256);

  // kv path: gather -> ip proj -> fused k|v proj (N=512)
  gather_nb<<<dim3(1024, 20), 256, 0, stream>>>(uid, nidx, item_emb, nb);
  gemm_nt<1><<<dim3(320, 4), 256, 0, stream>>>(nb, ip_w, ip_b, nullptr, kv, 20480, 256, 256);
  gemm_nt<1><<<dim3(320, 8), 256, 0, stream>>>(kv, ca_wqkv + 256 * 256, ca_bqkv + 256, nullptr,
                                               kvh, 20480, 512, 256);

  // attention core + out proj + LN1
  attn_k<<<1024, 256, 0, stream>>>(qh, kvh, o);
  gemm_nt<1><<<dim3(16, 4), 256, 0, stream>>>(o, ca_wo, ca_bo, nullptr, ca, 1024, 256, 256);
  ln_k<<<1024, 256, 0, stream>>>(qp, ca, n1_g, n1_b, h);

  // self-attn with seq=1 reduces to v-proj then o-proj
  gemm_nt<1><<<dim3(16, 4), 256, 0, stream>>>(h, sa_wqkv + 512 * 256, sa_bqkv + 512, nullptr,
                                              sav, 1024, 256, 256);
  gemm_nt<1><<<dim3(16, 4), 256, 0, stream>>>(sav, sa_wo, sa_bo, nullptr, sao, 1024, 256, 256);
  ln_k<<<1024, 256, 0, stream>>>(h, sao, n2_g, n2_b, h2);

  // FF + residual ; diffusion loss
  gemm_nt<2><<<dim3(16, 8), 256, 0, stream>>>(h2, ff_w1, ff_b1, nullptr, f1, 1024, 512, 256);
  gemm_nt<3><<<dim3(16, 4), 256, 0, stream>>>(f1, ff_w2, ff_b2, h2, zp, 1024, 256, 512);
  diff_k<<<1024, 256, 0, stream>>>(zp, z0, &scal[0]);

  // Decoder big GEMM with fused recon reduction
  gemm_nt<2><<<dim3(16, 8), 256, 0, stream>>>(z0, dec_w1, dec_b1, nullptr, G, 1024, 512, 256);
  dec_loss<<<dim3(8, 391), 256, 0, stream>>>(G, dec_w2, dec_b2, x0, &scal[1]);

  final_k<<<1, 1, 0, stream>>>(scal, (float*)d_out);
}

// Round 2
// 1086.950 us; speedup vs baseline: 1.2583x; 1.2583x over previous
//
#include <hip/hip_runtime.h>
#include <math.h>

#define NI   50000
#define Tt   1000
#define KP   50176              // 50000 padded to mult of 32*16 chunks
#define MW   1568               // mask words per row (KP/32)
#define NPAD 50048              // 391*128 n-pad for dec gemm

typedef __bf16 bf16x8 __attribute__((ext_vector_type(8)));
typedef float  f32x4  __attribute__((ext_vector_type(4)));

__device__ __forceinline__ unsigned short f2bf(float f) {
  unsigned u = __float_as_uint(f);
  u += 0x7FFFu + ((u >> 16) & 1u);   // RNE
  return (unsigned short)(u >> 16);
}
__device__ __forceinline__ unsigned pack2(float a, float b) {
  return (unsigned)f2bf(a) | ((unsigned)f2bf(b) << 16);
}
__device__ __forceinline__ void cvt_store4(unsigned short* d, float4 v) {
  ushort4 u; u.x = f2bf(v.x); u.y = f2bf(v.y); u.z = f2bf(v.z); u.w = f2bf(v.w);
  *(ushort4*)d = u;
}
__device__ __forceinline__ f32x4 mfma16(const unsigned short* a, const unsigned short* b, f32x4 c) {
  typedef unsigned short u16x8 __attribute__((ext_vector_type(8)));
  u16x8 av = *(const u16x8*)a;
  u16x8 bv = *(const u16x8*)b;
  return __builtin_amdgcn_mfma_f32_16x16x32_bf16(
      __builtin_bit_cast(bf16x8, av), __builtin_bit_cast(bf16x8, bv), c, 0, 0, 0);
}
__device__ __forceinline__ float gelu_f(float x) {
  return 0.5f * x * (1.f + erff(x * 0.70710678118654752f));
}

// async global->LDS, 16B per lane; LDS dest must be uniform base + lane*16
#define GLD16(gsrc, ldst) __builtin_amdgcn_global_load_lds( \
    (const __attribute__((address_space(1))) unsigned int*)(const void*)(gsrc), \
    (__attribute__((address_space(3))) unsigned int*)(void*)(ldst), 16, 0, 0)

// ---------------------------------------------------------------------------
// build_mask: x0 (1024 x 50000 f32, binary) -> bitmask (1024 x MW u32), pad=0
// ---------------------------------------------------------------------------
__global__ __launch_bounds__(256) void build_mask(
    const float* __restrict__ x0, unsigned int* __restrict__ xmask)
{
  int r = blockIdx.x;
  int w = threadIdx.x >> 6, l = threadIdx.x & 63;
  const float* row = x0 + (size_t)r * NI;
  unsigned long long* orow = (unsigned long long*)(xmask + (size_t)r * MW);
  for (int it = 0; it < 49; ++it) {
    int base = it * 1024 + w * 256;
#pragma unroll
    for (int j = 0; j < 4; ++j) {
      int k = base + j * 64 + l;
      float v = (k < NI) ? row[k] : 0.f;
      unsigned long long m = __ballot(v != 0.f);
      if (l == 0) orow[(base >> 6) + j] = m;
    }
  }
}

// enc_w1 (512 x 50000 f32) -> bf16 (512 x KP), k-pad zeroed
__global__ __launch_bounds__(256) void cvt_w1(const float* __restrict__ src,
                                              unsigned short* __restrict__ dst) {
  int c = blockIdx.x * 2048 + threadIdx.x * 8;
  if (c >= KP) return;
  int r = blockIdx.y;
  const float* s = src + (size_t)r * NI;
  uint4 o;
  if (c + 8 <= NI) {
    float4 a = *(const float4*)(s + c), b = *(const float4*)(s + c + 4);
    o.x = pack2(a.x, a.y); o.y = pack2(a.z, a.w);
    o.z = pack2(b.x, b.y); o.w = pack2(b.z, b.w);
  } else {
    float v[8];
#pragma unroll
    for (int i = 0; i < 8; ++i) v[i] = (c + i < NI) ? s[c + i] : 0.f;
    o.x = pack2(v[0], v[1]); o.y = pack2(v[2], v[3]);
    o.z = pack2(v[4], v[5]); o.w = pack2(v[6], v[7]);
  }
  *(uint4*)(dst + (size_t)r * KP + c) = o;
}

// dec_w2 (50000 x 512 f32) -> bf16 (NPAD x 512), straight cvt (pad rows unused)
__global__ __launch_bounds__(256) void cvt_w2n(const float* __restrict__ src,
                                               unsigned short* __restrict__ dst) {
  size_t idx = ((size_t)blockIdx.x * 256 + threadIdx.x) * 8;   // 12500 blocks exact
  float4 a = *(const float4*)(src + idx), b = *(const float4*)(src + idx + 4);
  uint4 o;
  o.x = pack2(a.x, a.y); o.y = pack2(a.z, a.w);
  o.z = pack2(b.x, b.y); o.w = pack2(b.z, b.w);
  *(uint4*)(dst + idx) = o;
}

// compose fused weights:
//  b<512 : Wkv[b,k] = sum_c ca_wqkv[256+b,c]*ip_w[c,k]  (bf16), bkv[b]=W.ip_b + bkv
//  b>=512: Wsa[i,k] = sum_c sa_wo[i,c]*sa_wqkv[512+c,k] (f32),  bsa[i]=wo.bv + bo
__global__ __launch_bounds__(256) void compose_k(
    const float* __restrict__ ca_wqkv, const float* __restrict__ ca_bqkv,
    const float* __restrict__ ip_w, const float* __restrict__ ip_b,
    const float* __restrict__ sa_wqkv, const float* __restrict__ sa_bqkv,
    const float* __restrict__ sa_wo, const float* __restrict__ sa_bo,
    unsigned short* __restrict__ Wkv, float* __restrict__ bkv,
    float* __restrict__ Wsa, float* __restrict__ bsa)
{
  int b = blockIdx.x, k = threadIdx.x;
  if (b < 512) {
    const float* wrow = ca_wqkv + (size_t)(256 + b) * 256;
    float s = 0.f;
    for (int c = 0; c < 256; ++c) s += wrow[c] * ip_w[c * 256 + k];
    Wkv[b * 256 + k] = f2bf(s);
    if (k == 0) {
      float sb = 0.f;
      for (int c = 0; c < 256; ++c) sb += wrow[c] * ip_b[c];
      bkv[b] = sb + ca_bqkv[256 + b];
    }
  } else {
    int i = b - 512;
    const float* worow = sa_wo + (size_t)i * 256;
    float s = 0.f;
    for (int c = 0; c < 256; ++c) s += worow[c] * sa_wqkv[(512 + c) * 256 + k];
    Wsa[i * 256 + k] = s;
    if (k == 0) {
      float sb = 0.f;
      for (int c = 0; c < 256; ++c) sb += worow[c] * sa_bqkv[512 + c];
      bsa[i] = sb + sa_bo[i];
    }
  }
}

// ---------------------------------------------------------------------------
// enc_mega: OUT(1024x512 f32, atomic) += bits(x0) @ w1b^T   m97-style
// grid (n=4, m=8, ksplit=16), chunk 3136 = 98 iters of BK=32
// ---------------------------------------------------------------------------
__global__ __launch_bounds__(256) void enc_mega(
    const unsigned int* __restrict__ xmask, const unsigned short* __restrict__ Bw,
    float* __restrict__ OUT)
{
  __shared__ __align__(16) unsigned short As[128 * 32];
  __shared__ __align__(16) unsigned short Bs[128 * 32];
  const int tid = threadIdx.x;
  const int n0 = blockIdx.x * 128;
  const int m0 = blockIdx.y * 128;
  const int kb = blockIdx.z * 3136;
  const int w = tid >> 6, l = tid & 63;
  const int wm = (w >> 1) * 64, wn = (w & 1) * 64;
  const int fr = l & 15, fo = (l >> 4) * 8;
  const int ar = tid >> 1, ah = tid & 1;
  const unsigned int* mrow = xmask + (size_t)m0 * MW;
  const int s0 = tid, s1 = tid + 256;
  f32x4 acc[4][4] = {};
  for (int it = 0; it < 98; ++it) {
    int k0 = kb + it * 32;
    __syncthreads();
    GLD16(Bw + (size_t)(n0 + (s0 >> 2)) * KP + k0 + (s0 & 3) * 8, &Bs[s0 * 8]);
    GLD16(Bw + (size_t)(n0 + (s1 >> 2)) * KP + k0 + (s1 & 3) * 8, &Bs[s1 * 8]);
    {
      unsigned word = mrow[(size_t)ar * MW + (k0 >> 5)];
      unsigned bits = word >> (ah * 16);
      uint4 q0, q1;
      q0.x = ((bits >> 0) & 1u ? 0x3F80u : 0u) | ((bits >> 1) & 1u ? 0x3F800000u : 0u);
      q0.y = ((bits >> 2) & 1u ? 0x3F80u : 0u) | ((bits >> 3) & 1u ? 0x3F800000u : 0u);
      q0.z = ((bits >> 4) & 1u ? 0x3F80u : 0u) | ((bits >> 5) & 1u ? 0x3F800000u : 0u);
      q0.w = ((bits >> 6) & 1u ? 0x3F80u : 0u) | ((bits >> 7) & 1u ? 0x3F800000u : 0u);
      q1.x = ((bits >> 8) & 1u ? 0x3F80u : 0u) | ((bits >> 9) & 1u ? 0x3F800000u : 0u);
      q1.y = ((bits >> 10) & 1u ? 0x3F80u : 0u) | ((bits >> 11) & 1u ? 0x3F800000u : 0u);
      q1.z = ((bits >> 12) & 1u ? 0x3F80u : 0u) | ((bits >> 13) & 1u ? 0x3F800000u : 0u);
      q1.w = ((bits >> 14) & 1u ? 0x3F80u : 0u) | ((bits >> 15) & 1u ? 0x3F800000u : 0u);
      unsigned short* dst = &As[ar * 32 + ah * 16];
      *(uint4*)dst = q0;
      *(uint4*)(dst + 8) = q1;
    }
    __syncthreads();
    const unsigned short *ap[4], *bp[4];
#pragma unroll
    for (int i = 0; i < 4; ++i) {
      ap[i] = &As[(wm + 16 * i + fr) * 32 + fo];
      bp[i] = &Bs[(wn + 16 * i + fr) * 32 + fo];
    }
#pragma unroll
    for (int i = 0; i < 4; ++i)
#pragma unroll
      for (int j = 0; j < 4; ++j)
        acc[i][j] = mfma16(ap[i], bp[j], acc[i][j]);
  }
  const int cr = (l >> 4) * 4, cc = l & 15;
#pragma unroll
  for (int i = 0; i < 4; ++i)
#pragma unroll
    for (int j = 0; j < 4; ++j) {
      int n = n0 + wn + 16 * j + cc;
#pragma unroll
      for (int r = 0; r < 4; ++r) {
        int m = m0 + wm + 16 * i + cr + r;
        atomicAdd(&OUT[(size_t)m * 512 + n], acc[i][j][r]);
      }
    }
}

// ---------------------------------------------------------------------------
// gemm_bt<EPI>: bf16 NT GEMM, m97-style (global_load_lds for A and B).
// EPI 0: C[m,n] = acc + bias[n] (f32 store)
// EPI 1: recon loss: sum softplus(acc+b[n]) - bit(m,n)*(acc+b[n]) -> atomicAdd
// ---------------------------------------------------------------------------
template<int EPI>
__global__ __launch_bounds__(256) void gemm_bt(
    const unsigned short* __restrict__ A, int lda,
    const unsigned short* __restrict__ Bw, int ldb,
    const float* __restrict__ bias,
    float* __restrict__ C, int ldc, int Klen,
    const unsigned int* __restrict__ xmask, float* __restrict__ loss, int Nvalid)
{
  __shared__ __align__(16) unsigned short As[128 * 32];
  __shared__ __align__(16) unsigned short Bs[128 * 32];
  __shared__ float red[4];
  const int tid = threadIdx.x;
  const int m0 = blockIdx.x * 128;
  const int n0 = blockIdx.y * 128;
  const int w = tid >> 6, l = tid & 63;
  const int wm = (w >> 1) * 64, wn = (w & 1) * 64;
  const int fr = l & 15, fo = (l >> 4) * 8;
  const int s0 = tid, s1 = tid + 256;
  const int iters = Klen >> 5;
  f32x4 acc[4][4] = {};
  for (int it = 0; it < iters; ++it) {
    int k0 = it * 32;
    __syncthreads();
    GLD16(A  + (size_t)(m0 + (s0 >> 2)) * lda + k0 + (s0 & 3) * 8, &As[s0 * 8]);
    GLD16(A  + (size_t)(m0 + (s1 >> 2)) * lda + k0 + (s1 & 3) * 8, &As[s1 * 8]);
    GLD16(Bw + (size_t)(n0 + (s0 >> 2)) * ldb + k0 + (s0 & 3) * 8, &Bs[s0 * 8]);
    GLD16(Bw + (size_t)(n0 + (s1 >> 2)) * ldb + k0 + (s1 & 3) * 8, &Bs[s1 * 8]);
    __syncthreads();
    const unsigned short *ap[4], *bp[4];
#pragma unroll
    for (int i = 0; i < 4; ++i) {
      ap[i] = &As[(wm + 16 * i + fr) * 32 + fo];
      bp[i] = &Bs[(wn + 16 * i + fr) * 32 + fo];
    }
#pragma unroll
    for (int i = 0; i < 4; ++i)
#pragma unroll
      for (int j = 0; j < 4; ++j)
        acc[i][j] = mfma16(ap[i], bp[j], acc[i][j]);
  }
  const int cr = (l >> 4) * 4, cc = l & 15;
  if (EPI == 0) {
#pragma unroll
    for (int j = 0; j < 4; ++j) {
      int n = n0 + wn + 16 * j + cc;
      float bv = bias[n];
#pragma unroll
      for (int i = 0; i < 4; ++i)
#pragma unroll
        for (int r = 0; r < 4; ++r) {
          int m = m0 + wm + 16 * i + cr + r;
          C[(size_t)m * ldc + n] = acc[i][j][r] + bv;
        }
    }
  } else {
    float ts = 0.f;
#pragma unroll
    for (int j = 0; j < 4; ++j) {
      int n = n0 + wn + 16 * j + cc;
      if (n < Nvalid) {
        float bv = bias[n];
        int wofs = n >> 5, bit = n & 31;
#pragma unroll
        for (int i = 0; i < 4; ++i)
#pragma unroll
          for (int r = 0; r < 4; ++r) {
            int m = m0 + wm + 16 * i + cr + r;
            float lg = acc[i][j][r] + bv;
            float sp = fmaxf(lg, 0.f) + __logf(1.f + __expf(-fabsf(lg)));
            unsigned word = xmask[(size_t)m * MW + wofs];
            ts += sp - (((word >> bit) & 1u) ? lg : 0.f);
          }
      }
    }
    for (int off = 32; off > 0; off >>= 1) ts += __shfl_xor(ts, off);
    if (l == 0) red[w] = ts;
    __syncthreads();
    if (tid == 0) atomicAdd(loss, red[0] + red[1] + red[2] + red[3]);
  }
}

// ---------------------------------------------------------------------------
// Small NT GEMM (f32 in, cvt-staged): C = epi(A[M,K] @ B[N,K]^T)
// EPI 1:+bias  2:gelu(+bias)  3:+bias+E  4:gelu(+bias)->bf16 store
// ---------------------------------------------------------------------------
template<int EPI>
__global__ __launch_bounds__(256) void gemm_nt(
    const float* __restrict__ A, const float* __restrict__ Bm,
    const float* __restrict__ bias, const float* __restrict__ E,
    float* __restrict__ C, int M, int N, int K)
{
  __shared__ __align__(16) unsigned short As[64 * 40];
  __shared__ __align__(16) unsigned short Bs[64 * 40];
  const int tid = threadIdx.x;
  const int m0 = blockIdx.x * 64, n0 = blockIdx.y * 64;
  const int w = tid >> 6, l = tid & 63;
  const int wm = (w >> 1) * 32, wn = (w & 1) * 32;
  const int sr = tid >> 3, sc = (tid & 7) * 4;
  const int fr = l & 15, fo = (l >> 4) * 8;
  f32x4 acc[2][2] = {};
  for (int k0 = 0; k0 < K; k0 += 32) {
#pragma unroll
    for (int half = 0; half < 2; ++half) {
      int row = sr + half * 32;
      cvt_store4(&As[row * 40 + sc], *(const float4*)(A  + (size_t)(m0 + row) * K + k0 + sc));
      cvt_store4(&Bs[row * 40 + sc], *(const float4*)(Bm + (size_t)(n0 + row) * K + k0 + sc));
    }
    __syncthreads();
    const unsigned short* ap0 = &As[(wm +      fr) * 40 + fo];
    const unsigned short* ap1 = &As[(wm + 16 + fr) * 40 + fo];
    const unsigned short* bp0 = &Bs[(wn +      fr) * 40 + fo];
    const unsigned short* bp1 = &Bs[(wn + 16 + fr) * 40 + fo];
    acc[0][0] = mfma16(ap0, bp0, acc[0][0]);
    acc[0][1] = mfma16(ap0, bp1, acc[0][1]);
    acc[1][0] = mfma16(ap1, bp0, acc[1][0]);
    acc[1][1] = mfma16(ap1, bp1, acc[1][1]);
    __syncthreads();
  }
  const int cr = (l >> 4) * 4, cc = l & 15;
#pragma unroll
  for (int i = 0; i < 2; ++i)
#pragma unroll
    for (int j = 0; j < 2; ++j) {
      int n = n0 + wn + 16 * j + cc;
      float bv = bias[n];
#pragma unroll
      for (int r = 0; r < 4; ++r) {
        int m = m0 + wm + 16 * i + cr + r;
        float v = acc[i][j][r] + bv;
        if (EPI == 2) v = gelu_f(v);
        if (EPI == 3) v += E[(size_t)m * N + n];
        if (EPI == 4) ((unsigned short*)C)[(size_t)m * N + n] = f2bf(gelu_f(v));
        else C[(size_t)m * N + n] = v;
      }
    }
}

// H1 = gelu(OUT + enc_b1), 1024x512
__global__ __launch_bounds__(256) void h1_epi(const float* __restrict__ S,
                                              const float* __restrict__ b,
                                              float* __restrict__ H) {
  int i = blockIdx.x * 256 + threadIdx.x;
  H[i] = gelu_f(S[i] + b[i & 511]);
}

// z_t / time-embedding prep
__global__ __launch_bounds__(256) void prep_k(
    const int* __restrict__ t, const float* __restrict__ z0, const float* __restrict__ noise,
    const float* __restrict__ te_w1, const float* __restrict__ te_b1,
    const float* __restrict__ te_w2, const float* __restrict__ te_b2,
    float* __restrict__ z_t, float* __restrict__ te)
{
  __shared__ float sj[32];
  __shared__ float sch[2];
  int b = blockIdx.x, d = threadIdx.x;
  int ti = t[b];
  float tn = (float)ti / (float)Tt;
  if (d < 32) {
    float a = tn * te_w1[d] + te_b1[d];
    sj[d] = a / (1.f + __expf(-a));
  }
  if (d == 0) {
    double tt = (double)(ti + 1) / (double)Tt;
    double c  = cos((tt + 0.008) / 1.008 * M_PI * 0.5);
    double c0 = cos((0.008) / 1.008 * M_PI * 0.5);
    double ab = (c * c) / (c0 * c0);
    sch[0] = (float)sqrt(ab);
    sch[1] = (float)sqrt(1.0 - ab);
  }
  __syncthreads();
  float accv = te_b2[d];
#pragma unroll
  for (int j = 0; j < 32; ++j) accv += sj[j] * te_w2[d * 32 + j];
  size_t i = (size_t)b * 256 + d;
  te[i]  = accv;
  z_t[i] = sch[0] * z0[i] + sch[1] * noise[i];
}

// gather neighbors -> bf16
__global__ __launch_bounds__(256) void gather_nb(
    const int* __restrict__ uid, const int* __restrict__ nidx,
    const float* __restrict__ emb, unsigned short* __restrict__ nb)
{
  int b = blockIdx.x, j = blockIdx.y, d = threadIdx.x;
  int idx = nidx[uid[b] * 20 + j];
  nb[((size_t)b * 20 + j) * 256 + d] = f2bf(emb[(size_t)idx * 256 + d]);
}

// cross-attention core: 20 keys, one wave per (b, head)
__global__ __launch_bounds__(256) void attn_k(
    const float* __restrict__ qh, const float* __restrict__ kvh, float* __restrict__ o)
{
  int b = blockIdx.x, tid = threadIdx.x;
  int h = tid >> 6, d = tid & 63;
  float qv = qh[(size_t)b * 256 + h * 64 + d];
  const float* kbase = kvh + (size_t)b * 20 * 512 + h * 64 + d;
  const float* vbase = kbase + 256;
  float s[20];
#pragma unroll
  for (int k = 0; k < 20; ++k) {
    float p = qv * kbase[k * 512];
    for (int off = 32; off > 0; off >>= 1) p += __shfl_xor(p, off);
    s[k] = p * 0.125f;
  }
  float mx = s[0];
#pragma unroll
  for (int k = 1; k < 20; ++k) mx = fmaxf(mx, s[k]);
  float sum = 0.f;
#pragma unroll
  for (int k = 0; k < 20; ++k) { s[k] = __expf(s[k] - mx); sum += s[k]; }
  float inv = 1.f / sum;
  float ov = 0.f;
#pragma unroll
  for (int k = 0; k < 20; ++k) ov += s[k] * vbase[k * 512];
  o[(size_t)b * 256 + h * 64 + d] = ov * inv;
}

// LayerNorm(X + Y)
__global__ __launch_bounds__(256) void ln_k(
    const float* __restrict__ X, const float* __restrict__ Y,
    const float* __restrict__ g, const float* __restrict__ bb, float* __restrict__ out)
{
  __shared__ float rs[4], rs2[4];
  int b = blockIdx.x, d = threadIdx.x;
  size_t i = (size_t)b * 256 + d;
  float v = X[i] + Y[i];
  float s = v, s2 = v * v;
  for (int off = 32; off > 0; off >>= 1) { s += __shfl_xor(s, off); s2 += __shfl_xor(s2, off); }
  int w = d >> 6, l = d & 63;
  if (l == 0) { rs[w] = s; rs2[w] = s2; }
  __syncthreads();
  s  = rs[0] + rs[1] + rs[2] + rs[3];
  s2 = rs2[0] + rs2[1] + rs2[2] + rs2[3];
  float mean = s * (1.f / 256.f);
  float var  = s2 * (1.f / 256.f) - mean * mean;
  out[i] = (v - mean) * rsqrtf(var + 1e-5f) * g[d] + bb[d];
}

// diff loss
__global__ __launch_bounds__(256) void diff_k(
    const float* __restrict__ zp, const float* __restrict__ z0, float* __restrict__ acc)
{
  __shared__ float red[4];
  size_t i = (size_t)blockIdx.x * 256 + threadIdx.x;
  float d = zp[i] - z0[i];
  float s = d * d;
  for (int off = 32; off > 0; off >>= 1) s += __shfl_xor(s, off);
  int w = threadIdx.x >> 6, l = threadIdx.x & 63;
  if (l == 0) red[w] = s;
  __syncthreads();
  if (threadIdx.x == 0) atomicAdd(acc, red[0] + red[1] + red[2] + red[3]);
}

__global__ void final_k(const float* __restrict__ scal, float* __restrict__ out) {
  out[0] = scal[0] * (1.f / (1024.f * 256.f)) + 0.1f * scal[1] * (1.f / (1024.f * 50000.f));
}

// ---------------------------------------------------------------------------
extern "C" void kernel_launch(void* const* d_in, const int* in_sizes, int n_in,
                              void* d_out, int out_size, void* d_ws, size_t ws_size,
                              hipStream_t stream) {
  const float* x0      = (const float*)d_in[0];
  const int*   uid     = (const int*)  d_in[1];
  const int*   t       = (const int*)  d_in[2];
  const float* noise   = (const float*)d_in[3];
  const int*   nidx    = (const int*)  d_in[4];
  const float* item_emb= (const float*)d_in[5];
  const float* enc_w1  = (const float*)d_in[6];
  const float* enc_b1  = (const float*)d_in[7];
  const float* enc_w2  = (const float*)d_in[8];
  const float* enc_b2  = (const float*)d_in[9];
  const float* dec_w1  = (const float*)d_in[10];
  const float* dec_b1  = (const float*)d_in[11];
  const float* dec_w2  = (const float*)d_in[12];
  const float* dec_b2  = (const float*)d_in[13];
  const float* up_w    = (const float*)d_in[14];
  const float* up_b    = (const float*)d_in[15];
  const float* ip_w    = (const float*)d_in[16];
  const float* ip_b    = (const float*)d_in[17];
  const float* te_w1   = (const float*)d_in[18];
  const float* te_b1   = (const float*)d_in[19];
  const float* te_w2   = (const float*)d_in[20];
  const float* te_b2   = (const float*)d_in[21];
  const float* ca_wqkv = (const float*)d_in[22];
  const float* ca_bqkv = (const float*)d_in[23];
  const float* ca_wo   = (const float*)d_in[24];
  const float* ca_bo   = (const float*)d_in[25];
  const float* sa_wqkv = (const float*)d_in[26];
  const float* sa_bqkv = (const float*)d_in[27];
  const float* sa_wo   = (const float*)d_in[28];
  const float* sa_bo   = (const float*)d_in[29];
  const float* n1_g    = (const float*)d_in[30];
  const float* n1_b    = (const float*)d_in[31];
  const float* n2_g    = (const float*)d_in[32];
  const float* n2_b    = (const float*)d_in[33];
  const float* ff_w1   = (const float*)d_in[34];
  const float* ff_b1   = (const float*)d_in[35];
  const float* ff_w2   = (const float*)d_in[36];
  const float* ff_b2   = (const float*)d_in[37];
  (void)in_sizes; (void)n_in; (void)out_size; (void)ws_size;

  float* ws   = (float*)d_ws;
  float* scal = ws;                         // 4
  float* OUT  = scal + 4;                   // 1024*512
  float* H1   = OUT + 524288;               // 1024*512
  float* z0   = H1  + 524288;
  float* zt   = z0  + 262144;
  float* te   = zt  + 262144;
  float* qp   = te  + 262144;
  float* qh   = qp  + 262144;
  float* o    = qh  + 262144;
  float* ca   = o   + 262144;
  float* h    = ca  + 262144;
  float* sao  = h   + 262144;
  float* h2   = sao + 262144;
  float* zp   = h2  + 262144;
  float* f1   = zp  + 262144;               // 1024*512
  float* kvh  = f1  + 524288;               // 20480*512 f32
  float* Wsa  = kvh + 10485760;             // 256*256
  float* bkv  = Wsa + 65536;                // 512
  float* bsa  = bkv + 512;                  // 256
  unsigned short* Wkv   = (unsigned short*)(bsa + 256);       // 512*256
  unsigned short* nb_bf = Wkv + 131072;                       // 20480*256
  unsigned short* Gbf   = nb_bf + 5242880;                    // 1024*512
  unsigned short* w1b   = Gbf + 524288;                       // 512*KP
  unsigned short* w2n   = w1b + (size_t)512 * KP;             // NPAD*512
  unsigned int*   xmask = (unsigned int*)(w2n + (size_t)NPAD * 512);  // 1024*MW

  hipMemsetAsync(d_ws, 0, (size_t)(4 + 524288) * sizeof(float), stream);

  // one-time conversions / compositions
  build_mask<<<1024, 256, 0, stream>>>(x0, xmask);
  cvt_w1<<<dim3(25, 512), 256, 0, stream>>>(enc_w1, w1b);
  cvt_w2n<<<12500, 256, 0, stream>>>(dec_w2, w2n);
  compose_k<<<768, 256, 0, stream>>>(ca_wqkv, ca_bqkv, ip_w, ip_b,
                                     sa_wqkv, sa_bqkv, sa_wo, sa_bo,
                                     Wkv, bkv, Wsa, bsa);

  // encoder big GEMM from bitmask (split-K 16, atomic f32)
  enc_mega<<<dim3(4, 8, 16), 256, 0, stream>>>(xmask, w1b, OUT);
  h1_epi<<<2048, 256, 0, stream>>>(OUT, enc_b1, H1);
  gemm_nt<1><<<dim3(16, 4), 256, 0, stream>>>(H1, enc_w2, enc_b2, nullptr, z0, 1024, 256, 512);

  // schedule + time embedding ; q path
  prep_k<<<1024, 256, 0, stream>>>(t, z0, noise, te_w1, te_b1, te_w2, te_b2, zt, te);
  gemm_nt<3><<<dim3(16, 4), 256, 0, stream>>>(zt, up_w, up_b, te, qp, 1024, 256, 256);
  gemm_nt<1><<<dim3(16, 4), 256, 0, stream>>>(qp, ca_wqkv, ca_bqkv, nullptr, qh, 1024, 256, 256);

  // kv path: gather -> fused (ip ∘ kv) projection via composed weight
  gather_nb<<<dim3(1024, 20), 256, 0, stream>>>(uid, nidx, item_emb, nb_bf);
  gemm_bt<0><<<dim3(160, 4), 256, 0, stream>>>(nb_bf, 256, Wkv, 256, bkv,
                                               kvh, 512, 256, nullptr, nullptr, 512);

  // attention core + out proj + LN1
  attn_k<<<1024, 256, 0, stream>>>(qh, kvh, o);
  gemm_nt<1><<<dim3(16, 4), 256, 0, stream>>>(o, ca_wo, ca_bo, nullptr, ca, 1024, 256, 256);
  ln_k<<<1024, 256, 0, stream>>>(qp, ca, n1_g, n1_b, h);

  // self-attn (seq=1) composed to one GEMM
  gemm_nt<1><<<dim3(16, 4), 256, 0, stream>>>(h, Wsa, bsa, nullptr, sao, 1024, 256, 256);
  ln_k<<<1024, 256, 0, stream>>>(h, sao, n2_g, n2_b, h2);

  // FF + residual ; diffusion loss
  gemm_nt<2><<<dim3(16, 8), 256, 0, stream>>>(h2, ff_w1, ff_b1, nullptr, f1, 1024, 512, 256);
  gemm_nt<3><<<dim3(16, 4), 256, 0, stream>>>(f1, ff_w2, ff_b2, h2, zp, 1024, 256, 512);
  diff_k<<<1024, 256, 0, stream>>>(zp, z0, &scal[0]);

  // decoder: G = gelu(z0@dec_w1^T+b) -> bf16 ; big GEMM + fused recon loss
  gemm_nt<4><<<dim3(16, 8), 256, 0, stream>>>(z0, dec_w1, dec_b1, nullptr,
                                              (float*)Gbf, 1024, 512, 256);
  gemm_bt<1><<<dim3(8, 391), 256, 0, stream>>>(Gbf, 512, w2n, 512, dec_b2,
                                               nullptr, 0, 512, xmask, &scal[1], NI);

  final_k<<<1, 1, 0, stream>>>(scal, (float*)d_out);
}

// Round 3
// 962.912 us; speedup vs baseline: 1.4203x; 1.1288x over previous
//
#include <hip/hip_runtime.h>
#include <math.h>

#define NI   50000
#define Tt   1000
#define KP   50176              // 50000 padded: 16 chunks x 3136 (=98*32)
#define MW   1568               // mask words per row (KP/32)
#define NPAD 50048              // 391*128 n-pad for dec gemm

typedef __bf16 bf16x8 __attribute__((ext_vector_type(8)));
typedef float  f32x4  __attribute__((ext_vector_type(4)));

__device__ __forceinline__ unsigned short f2bf(float f) {
  unsigned u = __float_as_uint(f);
  u += 0x7FFFu + ((u >> 16) & 1u);   // RNE
  return (unsigned short)(u >> 16);
}
__device__ __forceinline__ float bf2f(unsigned short u) {
  return __uint_as_float(((unsigned)u) << 16);
}
__device__ __forceinline__ unsigned pack2(float a, float b) {
  return (unsigned)f2bf(a) | ((unsigned)f2bf(b) << 16);
}
__device__ __forceinline__ f32x4 mfma16(const unsigned short* a, const unsigned short* b, f32x4 c) {
  typedef unsigned short u16x8 __attribute__((ext_vector_type(8)));
  u16x8 av = *(const u16x8*)a;
  u16x8 bv = *(const u16x8*)b;
  return __builtin_amdgcn_mfma_f32_16x16x32_bf16(
      __builtin_bit_cast(bf16x8, av), __builtin_bit_cast(bf16x8, bv), c, 0, 0, 0);
}
__device__ __forceinline__ float gelu_f(float x) {
  return 0.5f * x * (1.f + erff(x * 0.70710678118654752f));
}

#define GLD16(gsrc, ldst) __builtin_amdgcn_global_load_lds( \
    (const __attribute__((address_space(1))) unsigned int*)(const void*)(gsrc), \
    (__attribute__((address_space(3))) unsigned int*)(void*)(ldst), 16, 0, 0)

// ---------------------------------------------------------------------------
// bm_expand: x0 f32 -> xmask bits + x0b bf16 {0,1} (1024 x KP, pad 0)
// coalesced float4 reads; nibble assembly in LDS
// ---------------------------------------------------------------------------
__global__ __launch_bounds__(256) void bm_expand(
    const float* __restrict__ x0, unsigned int* __restrict__ xmask,
    unsigned short* __restrict__ x0b)
{
  __shared__ unsigned int nib[256];
  int r = blockIdx.x, tid = threadIdx.x;
  const float* row = x0 + (size_t)r * NI;
  unsigned short* orow = x0b + (size_t)r * KP;
  unsigned int* mrow = xmask + (size_t)r * MW;
  for (int pass = 0; pass < 49; ++pass) {
    int base = pass * 1024;
    int k = base + tid * 4;
    float4 v = make_float4(0.f, 0.f, 0.f, 0.f);
    if (k + 4 <= NI) v = *(const float4*)(row + k);      // NI % 4 == 0
    ushort4 ob;
    ob.x = v.x != 0.f ? 0x3F80 : 0; ob.y = v.y != 0.f ? 0x3F80 : 0;
    ob.z = v.z != 0.f ? 0x3F80 : 0; ob.w = v.w != 0.f ? 0x3F80 : 0;
    *(ushort4*)(orow + k) = ob;
    unsigned n4 = (v.x != 0.f ? 1u : 0u) | (v.y != 0.f ? 2u : 0u) |
                  (v.z != 0.f ? 4u : 0u) | (v.w != 0.f ? 8u : 0u);
    nib[tid] = n4;
    __syncthreads();
    if (tid < 32) {
      unsigned wv = 0;
#pragma unroll
      for (int j = 0; j < 8; ++j) wv |= nib[tid * 8 + j] << (4 * j);
      mrow[(base >> 5) + tid] = wv;
    }
    __syncthreads();
  }
}

// enc_w1 (512 x 50000 f32) -> bf16 (512 x KP), k-pad zeroed
__global__ __launch_bounds__(256) void cvt_w1(const float* __restrict__ src,
                                              unsigned short* __restrict__ dst) {
  int c = blockIdx.x * 2048 + threadIdx.x * 8;
  if (c >= KP) return;
  int r = blockIdx.y;
  const float* s = src + (size_t)r * NI;
  uint4 o;
  if (c + 8 <= NI) {
    float4 a = *(const float4*)(s + c), b = *(const float4*)(s + c + 4);
    o.x = pack2(a.x, a.y); o.y = pack2(a.z, a.w);
    o.z = pack2(b.x, b.y); o.w = pack2(b.z, b.w);
  } else {
    float v[8];
#pragma unroll
    for (int i = 0; i < 8; ++i) v[i] = (c + i < NI) ? s[c + i] : 0.f;
    o.x = pack2(v[0], v[1]); o.y = pack2(v[2], v[3]);
    o.z = pack2(v[4], v[5]); o.w = pack2(v[6], v[7]);
  }
  *(uint4*)(dst + (size_t)r * KP + c) = o;
}

// dec_w2 (50000 x 512 f32) -> bf16 straight cvt
__global__ __launch_bounds__(256) void cvt_w2n(const float* __restrict__ src,
                                               unsigned short* __restrict__ dst) {
  size_t idx = ((size_t)blockIdx.x * 256 + threadIdx.x) * 8;   // 12500 blocks exact
  float4 a = *(const float4*)(src + idx), b = *(const float4*)(src + idx + 4);
  uint4 o;
  o.x = pack2(a.x, a.y); o.y = pack2(a.z, a.w);
  o.z = pack2(b.x, b.y); o.w = pack2(b.z, b.w);
  *(uint4*)(dst + idx) = o;
}

// batch-convert 7 small weights f32->bf16
__global__ __launch_bounds__(256) void cvt_many(
    const float* s0, const float* s1, const float* s2, const float* s3,
    const float* s4, const float* s5, const float* s6,
    unsigned short* d0, unsigned short* d1, unsigned short* d2, unsigned short* d3,
    unsigned short* d4, unsigned short* d5, unsigned short* d6)
{
  const float* srcs[7] = {s0, s1, s2, s3, s4, s5, s6};
  unsigned short* dsts[7] = {d0, d1, d2, d3, d4, d5, d6};
  const int ns[7] = {131072, 65536, 65536, 65536, 131072, 131072, 131072};
  int j = blockIdx.y;
  int i = (blockIdx.x * 256 + threadIdx.x) * 8;
  if (i >= ns[j]) return;
  float4 a = *(const float4*)(srcs[j] + i), b = *(const float4*)(srcs[j] + i + 4);
  uint4 o;
  o.x = pack2(a.x, a.y); o.y = pack2(a.z, a.w);
  o.z = pack2(b.x, b.y); o.w = pack2(b.z, b.w);
  *(uint4*)(dsts[j] + i) = o;
}

// compose fused weights (kv-path and seq1-selfattn), bf16 outputs
__global__ __launch_bounds__(256) void compose_k(
    const float* __restrict__ ca_wqkv, const float* __restrict__ ca_bqkv,
    const float* __restrict__ ip_w, const float* __restrict__ ip_b,
    const float* __restrict__ sa_wqkv, const float* __restrict__ sa_bqkv,
    const float* __restrict__ sa_wo, const float* __restrict__ sa_bo,
    unsigned short* __restrict__ Wkv, float* __restrict__ bkv,
    unsigned short* __restrict__ Wsa, float* __restrict__ bsa)
{
  int b = blockIdx.x, k = threadIdx.x;
  if (b < 512) {
    const float* wrow = ca_wqkv + (size_t)(256 + b) * 256;
    float s = 0.f;
    for (int c = 0; c < 256; ++c) s += wrow[c] * ip_w[c * 256 + k];
    Wkv[b * 256 + k] = f2bf(s);
    if (k == 0) {
      float sb = 0.f;
      for (int c = 0; c < 256; ++c) sb += wrow[c] * ip_b[c];
      bkv[b] = sb + ca_bqkv[256 + b];
    }
  } else {
    int i = b - 512;
    const float* worow = sa_wo + (size_t)i * 256;
    float s = 0.f;
    for (int c = 0; c < 256; ++c) s += worow[c] * sa_wqkv[(512 + c) * 256 + k];
    Wsa[i * 256 + k] = f2bf(s);
    if (k == 0) {
      float sb = 0.f;
      for (int c = 0; c < 256; ++c) sb += worow[c] * sa_bqkv[512 + c];
      bsa[i] = sb + sa_bo[i];
    }
  }
}

// ---------------------------------------------------------------------------
// gemm128<T>: 128x128 tile, pure GLD16 staging (m97 structure)
// T0: C bf16 = acc + bias   T1: dec recon loss   T2: atomic f32 (split-K z)
// ---------------------------------------------------------------------------
template<int T>
__global__ __launch_bounds__(256) void gemm128(
    const unsigned short* __restrict__ A, int lda,
    const unsigned short* __restrict__ Bw, int ldb,
    const float* __restrict__ bias, void* __restrict__ Cv, int ldc, int K,
    const unsigned int* __restrict__ xmask, float* __restrict__ loss, int Nvalid)
{
  __shared__ __align__(16) unsigned short As[128 * 32];
  __shared__ __align__(16) unsigned short Bs[128 * 32];
  __shared__ unsigned int msk[128][4];
  __shared__ float red[4];
  const int tid = threadIdx.x;
  const int m0 = blockIdx.x * 128, n0 = blockIdx.y * 128;
  const int kb = (T == 2) ? blockIdx.z * K : 0;
  const int w = tid >> 6, l = tid & 63;
  const int wm = (w >> 1) * 64, wn = (w & 1) * 64;
  const int fr = l & 15, fo = (l >> 4) * 8;
  const int s0 = tid, s1 = tid + 256;
  const int iters = K >> 5;
  f32x4 acc[4][4] = {};
  for (int it = 0; it < iters; ++it) {
    int k0 = kb + it * 32;
    __syncthreads();
    GLD16(A  + (size_t)(m0 + (s0 >> 2)) * lda + k0 + (s0 & 3) * 8, &As[s0 * 8]);
    GLD16(A  + (size_t)(m0 + (s1 >> 2)) * lda + k0 + (s1 & 3) * 8, &As[s1 * 8]);
    GLD16(Bw + (size_t)(n0 + (s0 >> 2)) * ldb + k0 + (s0 & 3) * 8, &Bs[s0 * 8]);
    GLD16(Bw + (size_t)(n0 + (s1 >> 2)) * ldb + k0 + (s1 & 3) * 8, &Bs[s1 * 8]);
    __syncthreads();
    const unsigned short *ap[4], *bp[4];
#pragma unroll
    for (int i = 0; i < 4; ++i) {
      ap[i] = &As[(wm + 16 * i + fr) * 32 + fo];
      bp[i] = &Bs[(wn + 16 * i + fr) * 32 + fo];
    }
#pragma unroll
    for (int i = 0; i < 4; ++i)
#pragma unroll
      for (int j = 0; j < 4; ++j)
        acc[i][j] = mfma16(ap[i], bp[j], acc[i][j]);
  }
  const int cr = (l >> 4) * 4, cc = l & 15;
  if (T == 0) {
    unsigned short* Cb = (unsigned short*)Cv;
#pragma unroll
    for (int j = 0; j < 4; ++j) {
      int n = n0 + wn + 16 * j + cc;
      float bv = bias[n];
#pragma unroll
      for (int i = 0; i < 4; ++i)
#pragma unroll
        for (int r = 0; r < 4; ++r) {
          int m = m0 + wm + 16 * i + cr + r;
          Cb[(size_t)m * ldc + n] = f2bf(acc[i][j][r] + bv);
        }
    }
  } else if (T == 2) {
    float* Cf = (float*)Cv;
#pragma unroll
    for (int i = 0; i < 4; ++i)
#pragma unroll
      for (int j = 0; j < 4; ++j) {
        int n = n0 + wn + 16 * j + cc;
#pragma unroll
        for (int r = 0; r < 4; ++r) {
          int m = m0 + wm + 16 * i + cr + r;
          atomicAdd(&Cf[(size_t)m * ldc + n], acc[i][j][r]);
        }
      }
  } else {
    // stage this block's mask tile: 128 rows x 4 words
    {
      int row = tid >> 1, p = tid & 1;
      *(uint2*)&msk[row][p * 2] =
          *(const uint2*)(xmask + (size_t)(m0 + row) * MW + (n0 >> 5) + p * 2);
    }
    __syncthreads();
    float ts = 0.f;
#pragma unroll
    for (int j = 0; j < 4; ++j) {
      int nl = wn + 16 * j + cc;
      int n = n0 + nl;
      if (n < Nvalid) {
        float bv = bias[n];
#pragma unroll
        for (int i = 0; i < 4; ++i)
#pragma unroll
          for (int r = 0; r < 4; ++r) {
            int ml = wm + 16 * i + cr + r;
            float lg = acc[i][j][r] + bv;
            float sp = fmaxf(lg, 0.f) + __logf(1.f + __expf(-fabsf(lg)));
            unsigned word = msk[ml][nl >> 5];
            ts += sp - (((word >> (nl & 31)) & 1u) ? lg : 0.f);
          }
      }
    }
    for (int off = 32; off > 0; off >>= 1) ts += __shfl_xor(ts, off);
    if (l == 0) red[w] = ts;
    __syncthreads();
    if (tid == 0) atomicAdd(loss, red[0] + red[1] + red[2] + red[3]);
  }
}

// ---------------------------------------------------------------------------
// gemm64<EPI>: 64x64 tile GLD16 bf16 GEMM for the mid-chain
// EPI 0: f32 = acc+bias       1: bf16         2: gelu->bf16
//     3: z0 triple-write (z0f, z0b, ztb)      4: +te -> bf16 (qp)
//     5: ff2: +h2b residual, (v - z0f)^2 -> atomic loss
// ---------------------------------------------------------------------------
template<int EPI>
__global__ __launch_bounds__(256) void gemm64(
    const unsigned short* __restrict__ A, int lda,
    const unsigned short* __restrict__ Bw, int ldb,
    const float* __restrict__ bias, void* __restrict__ Cv, int ldc, int K,
    const void* __restrict__ R0, const void* __restrict__ R1, const void* __restrict__ R2,
    void* __restrict__ W0, void* __restrict__ W1, float* __restrict__ loss)
{
  __shared__ __align__(16) unsigned short As[64 * 32];
  __shared__ __align__(16) unsigned short Bs[64 * 32];
  __shared__ float red[4];
  const int tid = threadIdx.x;
  const int m0 = blockIdx.x * 64, n0 = blockIdx.y * 64;
  const int w = tid >> 6, l = tid & 63;
  const int wm = (w >> 1) * 32, wn = (w & 1) * 32;
  const int fr = l & 15, fo = (l >> 4) * 8;
  const int srow = tid >> 2, scol = (tid & 3) * 8;
  f32x4 acc[2][2] = {};
  for (int k0 = 0; k0 < K; k0 += 32) {
    __syncthreads();
    GLD16(A  + (size_t)(m0 + srow) * lda + k0 + scol, &As[tid * 8]);
    GLD16(Bw + (size_t)(n0 + srow) * ldb + k0 + scol, &Bs[tid * 8]);
    __syncthreads();
    const unsigned short* ap0 = &As[(wm +      fr) * 32 + fo];
    const unsigned short* ap1 = &As[(wm + 16 + fr) * 32 + fo];
    const unsigned short* bp0 = &Bs[(wn +      fr) * 32 + fo];
    const unsigned short* bp1 = &Bs[(wn + 16 + fr) * 32 + fo];
    acc[0][0] = mfma16(ap0, bp0, acc[0][0]);
    acc[0][1] = mfma16(ap0, bp1, acc[0][1]);
    acc[1][0] = mfma16(ap1, bp0, acc[1][0]);
    acc[1][1] = mfma16(ap1, bp1, acc[1][1]);
  }
  const int cr = (l >> 4) * 4, cc = l & 15;
  float ts = 0.f;
#pragma unroll
  for (int i = 0; i < 2; ++i)
#pragma unroll
    for (int j = 0; j < 2; ++j) {
      int n = n0 + wn + 16 * j + cc;
      float bv = bias[n];
#pragma unroll
      for (int r = 0; r < 4; ++r) {
        int m = m0 + wm + 16 * i + cr + r;
        float v = acc[i][j][r] + bv;
        size_t idx = (size_t)m * ldc + n;
        if (EPI == 0) ((float*)Cv)[idx] = v;
        if (EPI == 1) ((unsigned short*)Cv)[idx] = f2bf(v);
        if (EPI == 2) ((unsigned short*)Cv)[idx] = f2bf(gelu_f(v));
        if (EPI == 3) {
          ((float*)Cv)[idx] = v;
          ((unsigned short*)W0)[idx] = f2bf(v);
          float zt = ((const float*)R1)[m] * v +
                     ((const float*)R2)[m] * ((const float*)R0)[idx];
          ((unsigned short*)W1)[idx] = f2bf(zt);
        }
        if (EPI == 4) {
          v += ((const float*)R0)[idx];
          ((unsigned short*)Cv)[idx] = f2bf(v);
        }
        if (EPI == 5) {
          v += bf2f(((const unsigned short*)R0)[idx]);
          float d = v - ((const float*)R1)[idx];
          ts += d * d;
        }
      }
    }
  if (EPI == 5) {
    for (int off = 32; off > 0; off >>= 1) ts += __shfl_xor(ts, off);
    if (l == 0) red[w] = ts;
    __syncthreads();
    if (tid == 0) atomicAdd(loss, red[0] + red[1] + red[2] + red[3]);
  }
}

// H1b = gelu(OUT + enc_b1) -> bf16, 1024x512
__global__ __launch_bounds__(256) void h1_epi(const float* __restrict__ S,
                                              const float* __restrict__ b,
                                              unsigned short* __restrict__ H) {
  int i = blockIdx.x * 256 + threadIdx.x;
  H[i] = f2bf(gelu_f(S[i] + b[i & 511]));
}

// te row + per-row schedule scalars
__global__ __launch_bounds__(256) void prep_te(
    const int* __restrict__ t,
    const float* __restrict__ te_w1, const float* __restrict__ te_b1,
    const float* __restrict__ te_w2, const float* __restrict__ te_b2,
    float* __restrict__ te, float* __restrict__ sab, float* __restrict__ s1ab)
{
  __shared__ float sj[32];
  int b = blockIdx.x, d = threadIdx.x;
  int ti = t[b];
  float tn = (float)ti / (float)Tt;
  if (d < 32) {
    float a = tn * te_w1[d] + te_b1[d];
    sj[d] = a / (1.f + __expf(-a));
  }
  if (d == 0) {
    double tt = (double)(ti + 1) / (double)Tt;
    double c  = cos((tt + 0.008) / 1.008 * M_PI * 0.5);
    double c0 = cos((0.008) / 1.008 * M_PI * 0.5);
    double ab = (c * c) / (c0 * c0);
    sab[b]  = (float)sqrt(ab);
    s1ab[b] = (float)sqrt(1.0 - ab);
  }
  __syncthreads();
  float accv = te_b2[d];
#pragma unroll
  for (int j = 0; j < 32; ++j) accv += sj[j] * te_w2[d * 32 + j];
  te[(size_t)b * 256 + d] = accv;
}

// gather neighbors -> bf16
__global__ __launch_bounds__(256) void gather_nb(
    const int* __restrict__ uid, const int* __restrict__ nidx,
    const float* __restrict__ emb, unsigned short* __restrict__ nb)
{
  int b = blockIdx.x, j = blockIdx.y, d = threadIdx.x;
  int idx = nidx[uid[b] * 20 + j];
  nb[((size_t)b * 20 + j) * 256 + d] = f2bf(emb[(size_t)idx * 256 + d]);
}

// cross-attention core: 20 keys, one wave per (b, head); kvh bf16
__global__ __launch_bounds__(256) void attn_k(
    const float* __restrict__ qh, const unsigned short* __restrict__ kvh,
    unsigned short* __restrict__ o)
{
  int b = blockIdx.x, tid = threadIdx.x;
  int h = tid >> 6, d = tid & 63;
  float qv = qh[(size_t)b * 256 + h * 64 + d];
  const unsigned short* kbase = kvh + (size_t)b * 20 * 512 + h * 64 + d;
  const unsigned short* vbase = kbase + 256;
  float s[20];
#pragma unroll
  for (int k = 0; k < 20; ++k) {
    float p = qv * bf2f(kbase[k * 512]);
    for (int off = 32; off > 0; off >>= 1) p += __shfl_xor(p, off);
    s[k] = p * 0.125f;
  }
  float mx = s[0];
#pragma unroll
  for (int k = 1; k < 20; ++k) mx = fmaxf(mx, s[k]);
  float sum = 0.f;
#pragma unroll
  for (int k = 0; k < 20; ++k) { s[k] = __expf(s[k] - mx); sum += s[k]; }
  float inv = 1.f / sum;
  float ov = 0.f;
#pragma unroll
  for (int k = 0; k < 20; ++k) ov += s[k] * bf2f(vbase[k * 512]);
  o[(size_t)b * 256 + h * 64 + d] = f2bf(ov * inv);
}

// LayerNorm(X + Y), bf16 in/out
__global__ __launch_bounds__(256) void ln_k(
    const unsigned short* __restrict__ X, const unsigned short* __restrict__ Y,
    const float* __restrict__ g, const float* __restrict__ bb,
    unsigned short* __restrict__ out)
{
  __shared__ float rs[4], rs2[4];
  int b = blockIdx.x, d = threadIdx.x;
  size_t i = (size_t)b * 256 + d;
  float v = bf2f(X[i]) + bf2f(Y[i]);
  float s = v, s2 = v * v;
  for (int off = 32; off > 0; off >>= 1) { s += __shfl_xor(s, off); s2 += __shfl_xor(s2, off); }
  int w = d >> 6, l = d & 63;
  if (l == 0) { rs[w] = s; rs2[w] = s2; }
  __syncthreads();
  s  = rs[0] + rs[1] + rs[2] + rs[3];
  s2 = rs2[0] + rs2[1] + rs2[2] + rs2[3];
  float mean = s * (1.f / 256.f);
  float var  = s2 * (1.f / 256.f) - mean * mean;
  out[i] = f2bf((v - mean) * rsqrtf(var + 1e-5f) * g[d] + bb[d]);
}

__global__ void final_k(const float* __restrict__ scal, float* __restrict__ out) {
  out[0] = scal[0] * (1.f / (1024.f * 256.f)) + 0.1f * scal[1] * (1.f / (1024.f * 50000.f));
}

// ---------------------------------------------------------------------------
extern "C" void kernel_launch(void* const* d_in, const int* in_sizes, int n_in,
                              void* d_out, int out_size, void* d_ws, size_t ws_size,
                              hipStream_t stream) {
  const float* x0      = (const float*)d_in[0];
  const int*   uid     = (const int*)  d_in[1];
  const int*   t       = (const int*)  d_in[2];
  const float* noise   = (const float*)d_in[3];
  const int*   nidx    = (const int*)  d_in[4];
  const float* item_emb= (const float*)d_in[5];
  const float* enc_w1  = (const float*)d_in[6];
  const float* enc_b1  = (const float*)d_in[7];
  const float* enc_w2  = (const float*)d_in[8];
  const float* enc_b2  = (const float*)d_in[9];
  const float* dec_w1  = (const float*)d_in[10];
  const float* dec_b1  = (const float*)d_in[11];
  const float* dec_w2  = (const float*)d_in[12];
  const float* dec_b2  = (const float*)d_in[13];
  const float* up_w    = (const float*)d_in[14];
  const float* up_b    = (const float*)d_in[15];
  const float* ip_w    = (const float*)d_in[16];
  const float* ip_b    = (const float*)d_in[17];
  const float* te_w1   = (const float*)d_in[18];
  const float* te_b1   = (const float*)d_in[19];
  const float* te_w2   = (const float*)d_in[20];
  const float* te_b2   = (const float*)d_in[21];
  const float* ca_wqkv = (const float*)d_in[22];
  const float* ca_bqkv = (const float*)d_in[23];
  const float* ca_wo   = (const float*)d_in[24];
  const float* ca_bo   = (const float*)d_in[25];
  const float* sa_wqkv = (const float*)d_in[26];
  const float* sa_bqkv = (const float*)d_in[27];
  const float* sa_wo   = (const float*)d_in[28];
  const float* sa_bo   = (const float*)d_in[29];
  const float* n1_g    = (const float*)d_in[30];
  const float* n1_b    = (const float*)d_in[31];
  const float* n2_g    = (const float*)d_in[32];
  const float* n2_b    = (const float*)d_in[33];
  const float* ff_w1   = (const float*)d_in[34];
  const float* ff_b1   = (const float*)d_in[35];
  const float* ff_w2   = (const float*)d_in[36];
  const float* ff_b2   = (const float*)d_in[37];
  (void)in_sizes; (void)n_in; (void)out_size; (void)ws_size;

  float* ws   = (float*)d_ws;
  float* scal = ws;                    // 4 (diff, recon)
  float* OUT  = ws + 4;                // 1024*512 f32 (enc split-K atomic)
  float* sab  = OUT + 524288;          // 1024
  float* s1ab = sab + 1024;            // 1024
  float* te   = s1ab + 1024;           // 1024*256 f32
  float* qhf  = te + 262144;           // 1024*256 f32
  float* z0f  = qhf + 262144;          // 1024*256 f32
  float* bkv  = z0f + 262144;          // 512
  float* bsa  = bkv + 512;             // 256
  unsigned int* xmask = (unsigned int*)(bsa + 256);           // 1024*MW
  unsigned short* sh  = (unsigned short*)(xmask + 1024 * MW);
  unsigned short* x0b = sh;                                   // 1024*KP (aliased w2n)
  unsigned short* w2n = sh;                                   // NPAD*512 <= same region
  unsigned short* w1b = x0b + (size_t)1024 * KP;              // 512*KP
  unsigned short* nbb = w1b + (size_t)512 * KP;               // 20480*256
  unsigned short* kvhb= nbb + 5242880;                        // 20480*512
  unsigned short* H1b = kvhb + 10485760;                      // 1024*512
  unsigned short* z0b = H1b + 524288;
  unsigned short* ztb = z0b + 262144;
  unsigned short* qpb = ztb + 262144;
  unsigned short* ob  = qpb + 262144;
  unsigned short* cab = ob  + 262144;
  unsigned short* hb  = cab + 262144;
  unsigned short* saob= hb  + 262144;
  unsigned short* h2b = saob+ 262144;
  unsigned short* f1b = h2b + 262144;                         // 1024*512
  unsigned short* Gb  = f1b + 524288;                         // 1024*512
  unsigned short* enc_w2b = Gb + 524288;                      // 131072
  unsigned short* up_wb   = enc_w2b + 131072;
  unsigned short* ca_wqb  = up_wb + 65536;
  unsigned short* ca_wob  = ca_wqb + 65536;
  unsigned short* ff_w1b  = ca_wob + 65536;
  unsigned short* ff_w2b  = ff_w1b + 131072;
  unsigned short* dec_w1b = ff_w2b + 131072;
  unsigned short* Wkv     = dec_w1b + 131072;
  unsigned short* Wsab    = Wkv + 131072;

  hipMemsetAsync(d_ws, 0, (size_t)(4 + 524288) * sizeof(float), stream);

  // independent prep
  prep_te<<<1024, 256, 0, stream>>>(t, te_w1, te_b1, te_w2, te_b2, te, sab, s1ab);
  bm_expand<<<1024, 256, 0, stream>>>(x0, xmask, x0b);
  cvt_w1<<<dim3(25, 512), 256, 0, stream>>>(enc_w1, w1b);
  cvt_many<<<dim3(64, 7), 256, 0, stream>>>(enc_w2, up_w, ca_wqkv, ca_wo, ff_w1, ff_w2, dec_w1,
                                            enc_w2b, up_wb, ca_wqb, ca_wob, ff_w1b, ff_w2b, dec_w1b);
  compose_k<<<768, 256, 0, stream>>>(ca_wqkv, ca_bqkv, ip_w, ip_b,
                                     sa_wqkv, sa_bqkv, sa_wo, sa_bo,
                                     Wkv, bkv, Wsab, bsa);
  gather_nb<<<dim3(1024, 20), 256, 0, stream>>>(uid, nidx, item_emb, nbb);

  // encoder big GEMM: pure GLD16, split-K 16, atomic f32
  gemm128<2><<<dim3(8, 4, 16), 256, 0, stream>>>(
      x0b, KP, w1b, KP, nullptr, OUT, 512, 3136, nullptr, nullptr, 0);
  h1_epi<<<2048, 256, 0, stream>>>(OUT, enc_b1, H1b);

  // reuse x0b region for dec_w2 bf16 (x0b dead after enc GEMM)
  cvt_w2n<<<12500, 256, 0, stream>>>(dec_w2, w2n);

  // z0 GEMM + fused z_t
  gemm64<3><<<dim3(16, 4), 256, 0, stream>>>(
      H1b, 512, enc_w2b, 512, enc_b2, z0f, 256, 512, noise, sab, s1ab, z0b, ztb, nullptr);

  // q path
  gemm64<4><<<dim3(16, 4), 256, 0, stream>>>(
      ztb, 256, up_wb, 256, up_b, qpb, 256, 256, te, nullptr, nullptr, nullptr, nullptr, nullptr);
  gemm64<0><<<dim3(16, 4), 256, 0, stream>>>(
      qpb, 256, ca_wqb, 256, ca_bqkv, qhf, 256, 256,
      nullptr, nullptr, nullptr, nullptr, nullptr, nullptr);

  // kv path (composed ip∘kv weight)
  gemm128<0><<<dim3(160, 4), 256, 0, stream>>>(
      nbb, 256, Wkv, 256, bkv, kvhb, 512, 256, nullptr, nullptr, 0);

  // attention + out-proj + LN1
  attn_k<<<1024, 256, 0, stream>>>(qhf, kvhb, ob);
  gemm64<1><<<dim3(16, 4), 256, 0, stream>>>(
      ob, 256, ca_wob, 256, ca_bo, cab, 256, 256,
      nullptr, nullptr, nullptr, nullptr, nullptr, nullptr);
  ln_k<<<1024, 256, 0, stream>>>(qpb, cab, n1_g, n1_b, hb);

  // self-attn (seq=1, composed) + LN2
  gemm64<1><<<dim3(16, 4), 256, 0, stream>>>(
      hb, 256, Wsab, 256, bsa, saob, 256, 256,
      nullptr, nullptr, nullptr, nullptr, nullptr, nullptr);
  ln_k<<<1024, 256, 0, stream>>>(hb, saob, n2_g, n2_b, h2b);

  // FF with fused residual + diffusion loss
  gemm64<2><<<dim3(16, 8), 256, 0, stream>>>(
      h2b, 256, ff_w1b, 256, ff_b1, f1b, 512, 256,
      nullptr, nullptr, nullptr, nullptr, nullptr, nullptr);
  gemm64<5><<<dim3(16, 4), 256, 0, stream>>>(
      f1b, 512, ff_w2b, 512, ff_b2, nullptr, 256, 512,
      h2b, z0f, nullptr, nullptr, nullptr, &scal[0]);

  // decoder: G = gelu(z0@dec_w1^T+b) bf16, then big GEMM + fused recon loss
  gemm64<2><<<dim3(16, 8), 256, 0, stream>>>(
      z0b, 256, dec_w1b, 256, dec_b1, Gb, 512, 256,
      nullptr, nullptr, nullptr, nullptr, nullptr, nullptr);
  gemm128<1><<<dim3(8, 391), 256, 0, stream>>>(
      Gb, 512, w2n, 512, dec_b2, nullptr, 0, 512, xmask, &scal[1], NI);

  final_k<<<1, 1, 0, stream>>>(scal, (float*)d_out);
}

// Round 4
// 904.135 us; speedup vs baseline: 1.5127x; 1.0650x over previous
//
#include <hip/hip_runtime.h>
#include <math.h>

#define NI   50000
#define Tt   1000
#define KP   50176              // 50000 padded: 16 chunks x 3136 (=98*32)
#define MW   1568               // mask words per row (KP/32)
#define NPAD 50048              // 391*128 n-pad for dec gemm

typedef __bf16 bf16x8 __attribute__((ext_vector_type(8)));
typedef float  f32x4  __attribute__((ext_vector_type(4)));

__device__ __forceinline__ unsigned short f2bf(float f) {
  unsigned u = __float_as_uint(f);
  u += 0x7FFFu + ((u >> 16) & 1u);   // RNE
  return (unsigned short)(u >> 16);
}
__device__ __forceinline__ float bf2f(unsigned short u) {
  return __uint_as_float(((unsigned)u) << 16);
}
__device__ __forceinline__ unsigned pack2(float a, float b) {
  return (unsigned)f2bf(a) | ((unsigned)f2bf(b) << 16);
}
__device__ __forceinline__ f32x4 mfma16(const unsigned short* a, const unsigned short* b, f32x4 c) {
  typedef unsigned short u16x8 __attribute__((ext_vector_type(8)));
  u16x8 av = *(const u16x8*)a;
  u16x8 bv = *(const u16x8*)b;
  return __builtin_amdgcn_mfma_f32_16x16x32_bf16(
      __builtin_bit_cast(bf16x8, av), __builtin_bit_cast(bf16x8, bv), c, 0, 0, 0);
}
__device__ __forceinline__ float gelu_f(float x) {
  return 0.5f * x * (1.f + erff(x * 0.70710678118654752f));
}

#define GLD16(gsrc, ldst) __builtin_amdgcn_global_load_lds( \
    (const __attribute__((address_space(1))) unsigned int*)(const void*)(gsrc), \
    (__attribute__((address_space(3))) unsigned int*)(void*)(ldst), 16, 0, 0)

// ---------------------------------------------------------------------------
// bm_expand: x0 f32 -> xmask bits + x0b bf16 {0,1}; one barrier per block
// grid (25, 1024): y = row, x = 2048-elem chunk
// ---------------------------------------------------------------------------
__global__ __launch_bounds__(256) void bm_expand(
    const float* __restrict__ x0, unsigned int* __restrict__ xmask,
    unsigned short* __restrict__ x0b)
{
  __shared__ unsigned int nib[256];
  int r = blockIdx.y, tid = threadIdx.x;
  int c0 = blockIdx.x * 2048;
  int k = c0 + tid * 8;
  const float* row = x0 + (size_t)r * NI;
  float4 a = make_float4(0.f, 0.f, 0.f, 0.f), b = a;
  if (k + 8 <= NI) {                   // NI % 8 == 0
    a = *(const float4*)(row + k);
    b = *(const float4*)(row + k + 4);
  }
  uint4 o;
  o.x = (a.x != 0.f ? 0x3F80u : 0u) | (a.y != 0.f ? 0x3F800000u : 0u);
  o.y = (a.z != 0.f ? 0x3F80u : 0u) | (a.w != 0.f ? 0x3F800000u : 0u);
  o.z = (b.x != 0.f ? 0x3F80u : 0u) | (b.y != 0.f ? 0x3F800000u : 0u);
  o.w = (b.z != 0.f ? 0x3F80u : 0u) | (b.w != 0.f ? 0x3F800000u : 0u);
  if (k < KP) *(uint4*)(x0b + (size_t)r * KP + k) = o;
  unsigned bits8 =
      (a.x != 0.f ? 1u : 0u)  | (a.y != 0.f ? 2u : 0u)  |
      (a.z != 0.f ? 4u : 0u)  | (a.w != 0.f ? 8u : 0u)  |
      (b.x != 0.f ? 16u : 0u) | (b.y != 0.f ? 32u : 0u) |
      (b.z != 0.f ? 64u : 0u) | (b.w != 0.f ? 128u : 0u);
  nib[tid] = bits8;
  __syncthreads();
  if (tid < 64) {
    unsigned wv = nib[tid * 4] | (nib[tid * 4 + 1] << 8) |
                  (nib[tid * 4 + 2] << 16) | (nib[tid * 4 + 3] << 24);
    int widx = (c0 >> 5) + tid;
    if (widx < MW) xmask[(size_t)r * MW + widx] = wv;
  }
}

// enc_w1 (512 x 50000 f32) -> bf16 (512 x KP), k-pad zeroed
__global__ __launch_bounds__(256) void cvt_w1(const float* __restrict__ src,
                                              unsigned short* __restrict__ dst) {
  int c = blockIdx.x * 2048 + threadIdx.x * 8;
  if (c >= KP) return;
  int r = blockIdx.y;
  const float* s = src + (size_t)r * NI;
  uint4 o;
  if (c + 8 <= NI) {
    float4 a = *(const float4*)(s + c), b = *(const float4*)(s + c + 4);
    o.x = pack2(a.x, a.y); o.y = pack2(a.z, a.w);
    o.z = pack2(b.x, b.y); o.w = pack2(b.z, b.w);
  } else {
    float v[8];
#pragma unroll
    for (int i = 0; i < 8; ++i) v[i] = (c + i < NI) ? s[c + i] : 0.f;
    o.x = pack2(v[0], v[1]); o.y = pack2(v[2], v[3]);
    o.z = pack2(v[4], v[5]); o.w = pack2(v[6], v[7]);
  }
  *(uint4*)(dst + (size_t)r * KP + c) = o;
}

// dec_w2 (50000 x 512 f32) -> bf16 straight cvt
__global__ __launch_bounds__(256) void cvt_w2n(const float* __restrict__ src,
                                               unsigned short* __restrict__ dst) {
  size_t idx = ((size_t)blockIdx.x * 256 + threadIdx.x) * 8;   // 12500 blocks exact
  float4 a = *(const float4*)(src + idx), b = *(const float4*)(src + idx + 4);
  uint4 o;
  o.x = pack2(a.x, a.y); o.y = pack2(a.z, a.w);
  o.z = pack2(b.x, b.y); o.w = pack2(b.z, b.w);
  *(uint4*)(dst + idx) = o;
}

// batch-convert 7 small weights f32->bf16
__global__ __launch_bounds__(256) void cvt_many(
    const float* s0, const float* s1, const float* s2, const float* s3,
    const float* s4, const float* s5, const float* s6,
    unsigned short* d0, unsigned short* d1, unsigned short* d2, unsigned short* d3,
    unsigned short* d4, unsigned short* d5, unsigned short* d6)
{
  const float* srcs[7] = {s0, s1, s2, s3, s4, s5, s6};
  unsigned short* dsts[7] = {d0, d1, d2, d3, d4, d5, d6};
  const int ns[7] = {131072, 65536, 65536, 65536, 131072, 131072, 131072};
  int j = blockIdx.y;
  int i = (blockIdx.x * 256 + threadIdx.x) * 8;
  if (i >= ns[j]) return;
  float4 a = *(const float4*)(srcs[j] + i), b = *(const float4*)(srcs[j] + i + 4);
  uint4 o;
  o.x = pack2(a.x, a.y); o.y = pack2(a.z, a.w);
  o.z = pack2(b.x, b.y); o.w = pack2(b.z, b.w);
  *(uint4*)(dsts[j] + i) = o;
}

// compose fused weights (kv-path and seq1-selfattn), bf16 outputs
__global__ __launch_bounds__(256) void compose_k(
    const float* __restrict__ ca_wqkv, const float* __restrict__ ca_bqkv,
    const float* __restrict__ ip_w, const float* __restrict__ ip_b,
    const float* __restrict__ sa_wqkv, const float* __restrict__ sa_bqkv,
    const float* __restrict__ sa_wo, const float* __restrict__ sa_bo,
    unsigned short* __restrict__ Wkv, float* __restrict__ bkv,
    unsigned short* __restrict__ Wsa, float* __restrict__ bsa)
{
  int b = blockIdx.x, k = threadIdx.x;
  if (b < 512) {
    const float* wrow = ca_wqkv + (size_t)(256 + b) * 256;
    float s = 0.f;
    for (int c = 0; c < 256; ++c) s += wrow[c] * ip_w[c * 256 + k];
    Wkv[b * 256 + k] = f2bf(s);
    if (k == 0) {
      float sb = 0.f;
      for (int c = 0; c < 256; ++c) sb += wrow[c] * ip_b[c];
      bkv[b] = sb + ca_bqkv[256 + b];
    }
  } else {
    int i = b - 512;
    const float* worow = sa_wo + (size_t)i * 256;
    float s = 0.f;
    for (int c = 0; c < 256; ++c) s += worow[c] * sa_wqkv[(512 + c) * 256 + k];
    Wsa[i * 256 + k] = f2bf(s);
    if (k == 0) {
      float sb = 0.f;
      for (int c = 0; c < 256; ++c) sb += worow[c] * sa_bqkv[512 + c];
      bsa[i] = sb + sa_bo[i];
    }
  }
}

// ---------------------------------------------------------------------------
// gemm128<T>: 128x128 tile, pure GLD16 staging (m97 structure)
// T0: C bf16 = acc + bias (grid (mx,ny))
// T1: dec recon loss, linear grid 3136, XCD-swizzled, n-groups of 8 m-blocks
// T2: enc split-K -> per-split partial buffer, linear grid 512, XCD-swizzled
// ---------------------------------------------------------------------------
template<int T>
__global__ __launch_bounds__(256) void gemm128(
    const unsigned short* __restrict__ A, int lda,
    const unsigned short* __restrict__ Bw, int ldb,
    const float* __restrict__ bias, void* __restrict__ Cv, int ldc, int K,
    const unsigned int* __restrict__ xmask, float* __restrict__ loss, int Nvalid)
{
  __shared__ __align__(16) unsigned short As[128 * 32];
  __shared__ __align__(16) unsigned short Bs[128 * 32];
  __shared__ unsigned int msk[128][4];
  __shared__ float red[4];
  const int tid = threadIdx.x;
  int m0, n0, kb = 0, kc = 0, iters;
  if (T == 2) {
    // 512 blocks: g = n + 4*k (64 groups); same-g => same XCD (id%8 const)
    int id = blockIdx.x;
    int g = (id & 7) + 8 * (id >> 6);
    m0 = ((id >> 3) & 7) * 128;
    n0 = (g & 3) * 128;
    kc = g >> 2;                       // 16 k-splits
    kb = kc * 3136;
    iters = 98;
  } else if (T == 1) {
    // 3136 blocks: group = n-tile (391 used); 8 m-blocks per group on one XCD
    int id = blockIdx.x;
    int n = (id & 7) + 8 * (id >> 6);
    if (n >= 391) return;
    m0 = ((id >> 3) & 7) * 128;
    n0 = n * 128;
    iters = 16;
  } else {
    m0 = blockIdx.x * 128; n0 = blockIdx.y * 128;
    iters = K >> 5;
  }
  const int w = tid >> 6, l = tid & 63;
  const int wm = (w >> 1) * 64, wn = (w & 1) * 64;
  const int fr = l & 15, fo = (l >> 4) * 8;
  const int s0 = tid, s1 = tid + 256;
  f32x4 acc[4][4] = {};
  for (int it = 0; it < iters; ++it) {
    int k0 = kb + it * 32;
    __syncthreads();
    GLD16(A  + (size_t)(m0 + (s0 >> 2)) * lda + k0 + (s0 & 3) * 8, &As[s0 * 8]);
    GLD16(A  + (size_t)(m0 + (s1 >> 2)) * lda + k0 + (s1 & 3) * 8, &As[s1 * 8]);
    GLD16(Bw + (size_t)(n0 + (s0 >> 2)) * ldb + k0 + (s0 & 3) * 8, &Bs[s0 * 8]);
    GLD16(Bw + (size_t)(n0 + (s1 >> 2)) * ldb + k0 + (s1 & 3) * 8, &Bs[s1 * 8]);
    __syncthreads();
    const unsigned short *ap[4], *bp[4];
#pragma unroll
    for (int i = 0; i < 4; ++i) {
      ap[i] = &As[(wm + 16 * i + fr) * 32 + fo];
      bp[i] = &Bs[(wn + 16 * i + fr) * 32 + fo];
    }
#pragma unroll
    for (int i = 0; i < 4; ++i)
#pragma unroll
      for (int j = 0; j < 4; ++j)
        acc[i][j] = mfma16(ap[i], bp[j], acc[i][j]);
  }
  const int cr = (l >> 4) * 4, cc = l & 15;
  if (T == 0) {
    unsigned short* Cb = (unsigned short*)Cv;
#pragma unroll
    for (int j = 0; j < 4; ++j) {
      int n = n0 + wn + 16 * j + cc;
      float bv = bias[n];
#pragma unroll
      for (int i = 0; i < 4; ++i)
#pragma unroll
        for (int r = 0; r < 4; ++r) {
          int m = m0 + wm + 16 * i + cr + r;
          Cb[(size_t)m * ldc + n] = f2bf(acc[i][j][r] + bv);
        }
    }
  } else if (T == 2) {
    float* Cp = (float*)Cv + (size_t)kc * 524288;   // private split slice
#pragma unroll
    for (int i = 0; i < 4; ++i)
#pragma unroll
      for (int j = 0; j < 4; ++j) {
        int n = n0 + wn + 16 * j + cc;
#pragma unroll
        for (int r = 0; r < 4; ++r) {
          int m = m0 + wm + 16 * i + cr + r;
          Cp[(size_t)m * 512 + n] = acc[i][j][r];
        }
      }
  } else {
    // stage this block's mask tile: 128 rows x 4 words
    {
      int row = tid >> 1, p = tid & 1;
      *(uint2*)&msk[row][p * 2] =
          *(const uint2*)(xmask + (size_t)(m0 + row) * MW + (n0 >> 5) + p * 2);
    }
    __syncthreads();
    float ts = 0.f;
#pragma unroll
    for (int j = 0; j < 4; ++j) {
      int nl = wn + 16 * j + cc;
      int n = n0 + nl;
      if (n < Nvalid) {
        float bv = bias[n];
#pragma unroll
        for (int i = 0; i < 4; ++i)
#pragma unroll
          for (int r = 0; r < 4; ++r) {
            int ml = wm + 16 * i + cr + r;
            float lg = acc[i][j][r] + bv;
            float sp = fmaxf(lg, 0.f) + __logf(1.f + __expf(-fabsf(lg)));
            unsigned word = msk[ml][nl >> 5];
            ts += sp - (((word >> (nl & 31)) & 1u) ? lg : 0.f);
          }
      }
    }
    for (int off = 32; off > 0; off >>= 1) ts += __shfl_xor(ts, off);
    if (l == 0) red[w] = ts;
    __syncthreads();
    if (tid == 0) atomicAdd(loss, red[0] + red[1] + red[2] + red[3]);
  }
}

// ---------------------------------------------------------------------------
// gemm64<EPI>: 64x64 tile GLD16 bf16 GEMM for the mid-chain
// EPI 0: f32 = acc+bias       1: bf16         2: gelu->bf16
//     3: z0 triple-write (z0f, z0b, ztb)      4: +te -> bf16 (qp)
//     5: ff2: +h2b residual, (v - z0f)^2 -> atomic loss
// ---------------------------------------------------------------------------
template<int EPI>
__global__ __launch_bounds__(256) void gemm64(
    const unsigned short* __restrict__ A, int lda,
    const unsigned short* __restrict__ Bw, int ldb,
    const float* __restrict__ bias, void* __restrict__ Cv, int ldc, int K,
    const void* __restrict__ R0, const void* __restrict__ R1, const void* __restrict__ R2,
    void* __restrict__ W0, void* __restrict__ W1, float* __restrict__ loss)
{
  __shared__ __align__(16) unsigned short As[64 * 32];
  __shared__ __align__(16) unsigned short Bs[64 * 32];
  __shared__ float red[4];
  const int tid = threadIdx.x;
  const int m0 = blockIdx.x * 64, n0 = blockIdx.y * 64;
  const int w = tid >> 6, l = tid & 63;
  const int wm = (w >> 1) * 32, wn = (w & 1) * 32;
  const int fr = l & 15, fo = (l >> 4) * 8;
  const int srow = tid >> 2, scol = (tid & 3) * 8;
  f32x4 acc[2][2] = {};
  for (int k0 = 0; k0 < K; k0 += 32) {
    __syncthreads();
    GLD16(A  + (size_t)(m0 + srow) * lda + k0 + scol, &As[tid * 8]);
    GLD16(Bw + (size_t)(n0 + srow) * ldb + k0 + scol, &Bs[tid * 8]);
    __syncthreads();
    const unsigned short* ap0 = &As[(wm +      fr) * 32 + fo];
    const unsigned short* ap1 = &As[(wm + 16 + fr) * 32 + fo];
    const unsigned short* bp0 = &Bs[(wn +      fr) * 32 + fo];
    const unsigned short* bp1 = &Bs[(wn + 16 + fr) * 32 + fo];
    acc[0][0] = mfma16(ap0, bp0, acc[0][0]);
    acc[0][1] = mfma16(ap0, bp1, acc[0][1]);
    acc[1][0] = mfma16(ap1, bp0, acc[1][0]);
    acc[1][1] = mfma16(ap1, bp1, acc[1][1]);
  }
  const int cr = (l >> 4) * 4, cc = l & 15;
  float ts = 0.f;
#pragma unroll
  for (int i = 0; i < 2; ++i)
#pragma unroll
    for (int j = 0; j < 2; ++j) {
      int n = n0 + wn + 16 * j + cc;
      float bv = bias[n];
#pragma unroll
      for (int r = 0; r < 4; ++r) {
        int m = m0 + wm + 16 * i + cr + r;
        float v = acc[i][j][r] + bv;
        size_t idx = (size_t)m * ldc + n;
        if (EPI == 0) ((float*)Cv)[idx] = v;
        if (EPI == 1) ((unsigned short*)Cv)[idx] = f2bf(v);
        if (EPI == 2) ((unsigned short*)Cv)[idx] = f2bf(gelu_f(v));
        if (EPI == 3) {
          ((float*)Cv)[idx] = v;
          ((unsigned short*)W0)[idx] = f2bf(v);
          float zt = ((const float*)R1)[m] * v +
                     ((const float*)R2)[m] * ((const float*)R0)[idx];
          ((unsigned short*)W1)[idx] = f2bf(zt);
        }
        if (EPI == 4) {
          v += ((const float*)R0)[idx];
          ((unsigned short*)Cv)[idx] = f2bf(v);
        }
        if (EPI == 5) {
          v += bf2f(((const unsigned short*)R0)[idx]);
          float d = v - ((const float*)R1)[idx];
          ts += d * d;
        }
      }
    }
  if (EPI == 5) {
    for (int off = 32; off > 0; off >>= 1) ts += __shfl_xor(ts, off);
    if (l == 0) red[w] = ts;
    __syncthreads();
    if (tid == 0) atomicAdd(loss, red[0] + red[1] + red[2] + red[3]);
  }
}

// H1b = gelu(sum_k OUTp[k] + enc_b1) -> bf16, 1024x512; 16-slice split-K reduce
__global__ __launch_bounds__(256) void h1_epi(const float* __restrict__ P,
                                              const float* __restrict__ b,
                                              unsigned short* __restrict__ H) {
  int i = blockIdx.x * 256 + threadIdx.x;
  float s = b[i & 511];
#pragma unroll
  for (int k = 0; k < 16; ++k) s += P[(size_t)k * 524288 + i];
  H[i] = f2bf(gelu_f(s));
}

// te row + per-row schedule scalars
__global__ __launch_bounds__(256) void prep_te(
    const int* __restrict__ t,
    const float* __restrict__ te_w1, const float* __restrict__ te_b1,
    const float* __restrict__ te_w2, const float* __restrict__ te_b2,
    float* __restrict__ te, float* __restrict__ sab, float* __restrict__ s1ab)
{
  __shared__ float sj[32];
  int b = blockIdx.x, d = threadIdx.x;
  int ti = t[b];
  float tn = (float)ti / (float)Tt;
  if (d < 32) {
    float a = tn * te_w1[d] + te_b1[d];
    sj[d] = a / (1.f + __expf(-a));
  }
  if (d == 0) {
    double tt = (double)(ti + 1) / (double)Tt;
    double c  = cos((tt + 0.008) / 1.008 * M_PI * 0.5);
    double c0 = cos((0.008) / 1.008 * M_PI * 0.5);
    double ab = (c * c) / (c0 * c0);
    sab[b]  = (float)sqrt(ab);
    s1ab[b] = (float)sqrt(1.0 - ab);
  }
  __syncthreads();
  float accv = te_b2[d];
#pragma unroll
  for (int j = 0; j < 32; ++j) accv += sj[j] * te_w2[d * 32 + j];
  te[(size_t)b * 256 + d] = accv;
}

// gather neighbors -> bf16
__global__ __launch_bounds__(256) void gather_nb(
    const int* __restrict__ uid, const int* __restrict__ nidx,
    const float* __restrict__ emb, unsigned short* __restrict__ nb)
{
  int b = blockIdx.x, j = blockIdx.y, d = threadIdx.x;
  int idx = nidx[uid[b] * 20 + j];
  nb[((size_t)b * 20 + j) * 256 + d] = f2bf(emb[(size_t)idx * 256 + d]);
}

// cross-attention core: 20 keys, one wave per (b, head); kvh bf16
__global__ __launch_bounds__(256) void attn_k(
    const float* __restrict__ qh, const unsigned short* __restrict__ kvh,
    unsigned short* __restrict__ o)
{
  int b = blockIdx.x, tid = threadIdx.x;
  int h = tid >> 6, d = tid & 63;
  float qv = qh[(size_t)b * 256 + h * 64 + d];
  const unsigned short* kbase = kvh + (size_t)b * 20 * 512 + h * 64 + d;
  const unsigned short* vbase = kbase + 256;
  float s[20];
#pragma unroll
  for (int k = 0; k < 20; ++k) {
    float p = qv * bf2f(kbase[k * 512]);
    for (int off = 32; off > 0; off >>= 1) p += __shfl_xor(p, off);
    s[k] = p * 0.125f;
  }
  float mx = s[0];
#pragma unroll
  for (int k = 1; k < 20; ++k) mx = fmaxf(mx, s[k]);
  float sum = 0.f;
#pragma unroll
  for (int k = 0; k < 20; ++k) { s[k] = __expf(s[k] - mx); sum += s[k]; }
  float inv = 1.f / sum;
  float ov = 0.f;
#pragma unroll
  for (int k = 0; k < 20; ++k) ov += s[k] * bf2f(vbase[k * 512]);
  o[(size_t)b * 256 + h * 64 + d] = f2bf(ov * inv);
}

// LayerNorm(X + Y), bf16 in/out
__global__ __launch_bounds__(256) void ln_k(
    const unsigned short* __restrict__ X, const unsigned short* __restrict__ Y,
    const float* __restrict__ g, const float* __restrict__ bb,
    unsigned short* __restrict__ out)
{
  __shared__ float rs[4], rs2[4];
  int b = blockIdx.x, d = threadIdx.x;
  size_t i = (size_t)b * 256 + d;
  float v = bf2f(X[i]) + bf2f(Y[i]);
  float s = v, s2 = v * v;
  for (int off = 32; off > 0; off >>= 1) { s += __shfl_xor(s, off); s2 += __shfl_xor(s2, off); }
  int w = d >> 6, l = d & 63;
  if (l == 0) { rs[w] = s; rs2[w] = s2; }
  __syncthreads();
  s  = rs[0] + rs[1] + rs[2] + rs[3];
  s2 = rs2[0] + rs2[1] + rs2[2] + rs2[3];
  float mean = s * (1.f / 256.f);
  float var  = s2 * (1.f / 256.f) - mean * mean;
  out[i] = f2bf((v - mean) * rsqrtf(var + 1e-5f) * g[d] + bb[d]);
}

__global__ void final_k(const float* __restrict__ scal, float* __restrict__ out) {
  out[0] = scal[0] * (1.f / (1024.f * 256.f)) + 0.1f * scal[1] * (1.f / (1024.f * 50000.f));
}

// ---------------------------------------------------------------------------
extern "C" void kernel_launch(void* const* d_in, const int* in_sizes, int n_in,
                              void* d_out, int out_size, void* d_ws, size_t ws_size,
                              hipStream_t stream) {
  const float* x0      = (const float*)d_in[0];
  const int*   uid     = (const int*)  d_in[1];
  const int*   t       = (const int*)  d_in[2];
  const float* noise   = (const float*)d_in[3];
  const int*   nidx    = (const int*)  d_in[4];
  const float* item_emb= (const float*)d_in[5];
  const float* enc_w1  = (const float*)d_in[6];
  const float* enc_b1  = (const float*)d_in[7];
  const float* enc_w2  = (const float*)d_in[8];
  const float* enc_b2  = (const float*)d_in[9];
  const float* dec_w1  = (const float*)d_in[10];
  const float* dec_b1  = (const float*)d_in[11];
  const float* dec_w2  = (const float*)d_in[12];
  const float* dec_b2  = (const float*)d_in[13];
  const float* up_w    = (const float*)d_in[14];
  const float* up_b    = (const float*)d_in[15];
  const float* ip_w    = (const float*)d_in[16];
  const float* ip_b    = (const float*)d_in[17];
  const float* te_w1   = (const float*)d_in[18];
  const float* te_b1   = (const float*)d_in[19];
  const float* te_w2   = (const float*)d_in[20];
  const float* te_b2   = (const float*)d_in[21];
  const float* ca_wqkv = (const float*)d_in[22];
  const float* ca_bqkv = (const float*)d_in[23];
  const float* ca_wo   = (const float*)d_in[24];
  const float* ca_bo   = (const float*)d_in[25];
  const float* sa_wqkv = (const float*)d_in[26];
  const float* sa_bqkv = (const float*)d_in[27];
  const float* sa_wo   = (const float*)d_in[28];
  const float* sa_bo   = (const float*)d_in[29];
  const float* n1_g    = (const float*)d_in[30];
  const float* n1_b    = (const float*)d_in[31];
  const float* n2_g    = (const float*)d_in[32];
  const float* n2_b    = (const float*)d_in[33];
  const float* ff_w1   = (const float*)d_in[34];
  const float* ff_b1   = (const float*)d_in[35];
  const float* ff_w2   = (const float*)d_in[36];
  const float* ff_b2   = (const float*)d_in[37];
  (void)in_sizes; (void)n_in; (void)out_size; (void)ws_size;

  float* ws   = (float*)d_ws;
  float* scal = ws;                    // 4 (diff, recon)
  float* sab  = ws + 4;                // 1024
  float* s1ab = sab + 1024;
  float* te   = s1ab + 1024;           // 1024*256
  float* qhf  = te + 262144;           // 1024*256
  float* z0f  = qhf + 262144;          // 1024*256
  float* bkv  = z0f + 262144;          // 512
  float* bsa  = bkv + 512;             // 256
  unsigned int* xmask = (unsigned int*)(bsa + 256);           // 1024*MW
  // P-pool: OUTp (16 x 1024x512 f32 = 33,554,432 B) aliases exactly
  // [nbb | kvhb | f1b | Gb] (same byte size) — those are written post-h1_epi
  unsigned short* sh  = (unsigned short*)(xmask + 1024 * MW);
  float*          OUTp = (float*)sh;                          // 8,388,608 f32
  unsigned short* nbb  = sh;                                  // 20480*256
  unsigned short* kvhb = nbb + 5242880;                       // 20480*512
  unsigned short* f1b  = kvhb + 10485760;                     // 1024*512
  unsigned short* Gb   = f1b + 524288;                        // 1024*512
  unsigned short* x0b  = Gb + 524288;                         // 1024*KP (aliased w2n)
  unsigned short* w2n  = x0b;                                 // NPAD*512 <= x0b size
  unsigned short* w1b  = x0b + (size_t)1024 * KP;             // 512*KP
  unsigned short* H1b  = w1b + (size_t)512 * KP;              // 1024*512
  unsigned short* z0b  = H1b + 524288;
  unsigned short* ztb  = z0b + 262144;
  unsigned short* qpb  = ztb + 262144;
  unsigned short* ob   = qpb + 262144;
  unsigned short* cab  = ob  + 262144;
  unsigned short* hb   = cab + 262144;
  unsigned short* saob = hb  + 262144;
  unsigned short* h2b  = saob+ 262144;
  unsigned short* enc_w2b = h2b + 262144;                     // 131072
  unsigned short* up_wb   = enc_w2b + 131072;
  unsigned short* ca_wqb  = up_wb + 65536;
  unsigned short* ca_wob  = ca_wqb + 65536;
  unsigned short* ff_w1b  = ca_wob + 65536;
  unsigned short* ff_w2b  = ff_w1b + 131072;
  unsigned short* dec_w1b = ff_w2b + 131072;
  unsigned short* Wkv     = dec_w1b + 131072;
  unsigned short* Wsab    = Wkv + 131072;

  hipMemsetAsync(scal, 0, 4 * sizeof(float), stream);

  // independent prep
  prep_te<<<1024, 256, 0, stream>>>(t, te_w1, te_b1, te_w2, te_b2, te, sab, s1ab);
  bm_expand<<<dim3(25, 1024), 256, 0, stream>>>(x0, xmask, x0b);
  cvt_w1<<<dim3(25, 512), 256, 0, stream>>>(enc_w1, w1b);
  cvt_many<<<dim3(64, 7), 256, 0, stream>>>(enc_w2, up_w, ca_wqkv, ca_wo, ff_w1, ff_w2, dec_w1,
                                            enc_w2b, up_wb, ca_wqb, ca_wob, ff_w1b, ff_w2b, dec_w1b);
  compose_k<<<768, 256, 0, stream>>>(ca_wqkv, ca_bqkv, ip_w, ip_b,
                                     sa_wqkv, sa_bqkv, sa_wo, sa_bo,
                                     Wkv, bkv, Wsab, bsa);

  // encoder big GEMM: split-K 16 -> private partial slices (no atomics), swizzled
  gemm128<2><<<512, 256, 0, stream>>>(
      x0b, KP, w1b, KP, nullptr, OUTp, 512, 3136, nullptr, nullptr, 0);
  h1_epi<<<2048, 256, 0, stream>>>(OUTp, enc_b1, H1b);   // OUTp dead after this

  // reuse x0b region for dec_w2 bf16 (x0b dead after enc GEMM)
  cvt_w2n<<<12500, 256, 0, stream>>>(dec_w2, w2n);

  // kv path (P-pool live again: OUTp dead)
  gather_nb<<<dim3(1024, 20), 256, 0, stream>>>(uid, nidx, item_emb, nbb);
  gemm128<0><<<dim3(160, 4), 256, 0, stream>>>(
      nbb, 256, Wkv, 256, bkv, kvhb, 512, 256, nullptr, nullptr, 0);

  // z0 GEMM + fused z_t
  gemm64<3><<<dim3(16, 4), 256, 0, stream>>>(
      H1b, 512, enc_w2b, 512, enc_b2, z0f, 256, 512, noise, sab, s1ab, z0b, ztb, nullptr);

  // q path
  gemm64<4><<<dim3(16, 4), 256, 0, stream>>>(
      ztb, 256, up_wb, 256, up_b, qpb, 256, 256, te, nullptr, nullptr, nullptr, nullptr, nullptr);
  gemm64<0><<<dim3(16, 4), 256, 0, stream>>>(
      qpb, 256, ca_wqb, 256, ca_bqkv, qhf, 256, 256,
      nullptr, nullptr, nullptr, nullptr, nullptr, nullptr);

  // attention + out-proj + LN1
  attn_k<<<1024, 256, 0, stream>>>(qhf, kvhb, ob);
  gemm64<1><<<dim3(16, 4), 256, 0, stream>>>(
      ob, 256, ca_wob, 256, ca_bo, cab, 256, 256,
      nullptr, nullptr, nullptr, nullptr, nullptr, nullptr);
  ln_k<<<1024, 256, 0, stream>>>(qpb, cab, n1_g, n1_b, hb);

  // self-attn (seq=1, composed) + LN2
  gemm64<1><<<dim3(16, 4), 256, 0, stream>>>(
      hb, 256, Wsab, 256, bsa, saob, 256, 256,
      nullptr, nullptr, nullptr, nullptr, nullptr, nullptr);
  ln_k<<<1024, 256, 0, stream>>>(hb, saob, n2_g, n2_b, h2b);

  // FF with fused residual + diffusion loss
  gemm64<2><<<dim3(16, 8), 256, 0, stream>>>(
      h2b, 256, ff_w1b, 256, ff_b1, f1b, 512, 256,
      nullptr, nullptr, nullptr, nullptr, nullptr, nullptr);
  gemm64<5><<<dim3(16, 4), 256, 0, stream>>>(
      f1b, 512, ff_w2b, 512, ff_b2, nullptr, 256, 512,
      h2b, z0f, nullptr, nullptr, nullptr, &scal[0]);

  // decoder: G = gelu(z0@dec_w1^T+b) bf16, then big GEMM + fused recon loss
  gemm64<2><<<dim3(16, 8), 256, 0, stream>>>(
      z0b, 256, dec_w1b, 256, dec_b1, Gb, 512, 256,
      nullptr, nullptr, nullptr, nullptr, nullptr, nullptr);
  gemm128<1><<<3136, 256, 0, stream>>>(
      Gb, 512, w2n, 512, dec_b2, nullptr, 0, 512, xmask, &scal[1], NI);

  final_k<<<1, 1, 0, stream>>>(scal, (float*)d_out);
}